// Round 3
// baseline (740.014 us; speedup 1.0000x reference)
//
#include <hip/hip_runtime.h>
#include <hip/hip_bf16.h>
#include <hip/hip_fp8.h>

#define B_TOTAL 131072

typedef __attribute__((ext_vector_type(8))) short short8;   // 8 bf16 MFMA A/B frag
typedef __attribute__((ext_vector_type(4))) float f32x4;    // MFMA C/D frag
typedef unsigned int uint;

#define MFMA(a,b,c) __builtin_amdgcn_mfma_f32_16x16x32_bf16(a,b,c,0,0,0)
#define MFMA8(a,b,c) __builtin_amdgcn_mfma_f32_16x16x32_fp8_fp8(a,b,c,0,0,0)

__device__ __forceinline__ short f2bf(float f) {
  union { float f; uint u; } x; x.f = f;
  uint r = x.u + 0x7fffu + ((x.u >> 16) & 1u);  // RTNE
  return (short)(r >> 16);
}
__device__ __forceinline__ unsigned char f2fp8(float v) {
  union { __hip_fp8_e4m3 q; unsigned char b; } u;
  u.q = __hip_fp8_e4m3(v);
  return u.b;
}

__device__ __forceinline__ void gl_lds16(const void* g, void* l) {
  __builtin_amdgcn_global_load_lds((const __attribute__((address_space(1))) uint*)g,
                                   (__attribute__((address_space(3))) uint*)l, 16, 0, 0);
}
// 16B-chunk swizzles (writer & reader use the same involution)
__device__ __forceinline__ int swz4(int c, int r) { return (c & ~3) | ((c ^ r ^ (r >> 2)) & 3); }
__device__ __forceinline__ int swz8(int c, int r) { return (c & ~7) | ((c ^ r) & 7); }

// ---- weight convert+transpose: w[K][N] f32 -> wt[N][Kpad] bf16 (zero pad) ----
__global__ void conv_wT(const float* __restrict__ w, short* __restrict__ wt,
                        int K, int N, int Kpad) {
  const int i = blockIdx.x * 256 + threadIdx.x;
  if (i >= N * Kpad) return;
  const int n = i / Kpad, k = i % Kpad;
  wt[(long)n * Kpad + k] = (k < K) ? f2bf(w[(long)k * N + n]) : (short)0;
}

// ---- w3 [512][256] f32 -> w3f [256 n][512 k] fp8 ----
__global__ void conv_w3f8(const float* __restrict__ w, unsigned char* __restrict__ wt) {
  const int i = blockIdx.x * 256 + threadIdx.x;
  if (i >= 256 * 512) return;
  const int n = i >> 9, k = i & 511;
  wt[i] = f2fp8(w[k * 256 + n]);
}

// ---- small weights: pwT[16][256], qw1T[128][32], qw2T[16][128] (zero-padded) ----
__global__ void conv_small(const float* __restrict__ pw, const float* __restrict__ qw1,
                           const float* __restrict__ qw2, short* __restrict__ pwT,
                           short* __restrict__ qw1T, short* __restrict__ qw2T) {
  int t = blockIdx.x * 256 + threadIdx.x;
  if (t < 4096) { int c = t >> 8, k = t & 255; pwT[t] = (c < 13) ? f2bf(pw[k * 13 + c]) : (short)0; }
  else if (t < 8192) { int i = t - 4096; int j = i >> 5, k = i & 31;
    qw1T[i] = (k < 3) ? f2bf(qw1[k * 128 + j]) : (short)0; }
  else if (t < 10240) { int i = t - 8192; int c = i >> 7, j = i & 127;
    qw2T[i] = (c < 13) ? f2bf(qw2[j * 13 + c]) : (short)0; }
}

// ============ K1: enc (on the fly) -> h1 (chunked in regs) -> h2 (fp8) ============
__global__ __launch_bounds__(512)
void k1(const float* __restrict__ state, const float* __restrict__ action,
        const float* __restrict__ sensors,
        const short* __restrict__ w1T, const float* __restrict__ bb1,
        const short* __restrict__ w2T, const float* __restrict__ bb2,
        unsigned char* __restrict__ h2out) {
  __shared__ __align__(16) char lds[155648];
  short* encS = (short*)lds;                    // [64][72ch] swz8  (73728 B)
  char*  bReg = lds + 73728;                    // B1 dbuf 2x24576 / B2 dbuf 2x32768
  short* h1cS = (short*)(lds + 73728 + 65536);  // [64][128] swz8 (16384 B)
  float* svS  = (float*)h1cS;                   // [64*17] during enc build only
  float* wxS  = svS + 64 * 17;                  // [64*32]

  const int tid = threadIdx.x;
  const int wave = tid >> 6, lane = tid & 63;
  const int fr = lane & 15, fg = lane >> 4;
  const long rb = (long)blockIdx.x * 64;

  // ---- enc build ----
  for (int i = tid; i < 64 * 17; i += 512) {
    int r = i / 17, c = i % 17;
    svS[i] = (c < 13) ? state[(rb + r) * 13 + c] : action[(rb + r) * 4 + (c - 13)];
  }
  __syncthreads();
  for (int i = tid; i < 64 * 32; i += 512) {
    int r = i >> 5, s = i & 31;
    float dx = sensors[s * 3 + 0] - svS[r * 17 + 0];
    float dy = sensors[s * 3 + 1] - svS[r * 17 + 1];
    float dz = sensors[s * 3 + 2] - svS[r * 17 + 2];
    wxS[i] = __expf(-2.f * sqrtf(dx * dx + dy * dy + dz * dz));
  }
  __syncthreads();
  for (int i = tid; i < 64 * 72; i += 512) {
    int r = i / 72, c8 = i % 72;
    short8 v;
#pragma unroll
    for (int j = 0; j < 8; ++j) {
      int k = c8 * 8 + j;
      float f = 0.f;
      if (k < 544) { int s = k / 17, c = k % 17; f = svS[r * 17 + c] * wxS[r * 32 + s]; }
      v[j] = f2bf(f);
    }
    *(short8*)&encS[(r * 72 + swz8(c8, r)) * 8] = v;
  }

  const int wr1 = (wave >> 2) * 32, wc1 = (wave & 3) * 32;    // h1c [64][128] tile
  const int wrH = (wave >> 2) * 32, wcH = (wave & 3) * 128;   // h2  [64][512] tile

  f32x4 acc2[2][8] = {};

  for (int ch = 0; ch < 8; ++ch) {
    __syncthreads();  // prev-phase B/h1c reads done (and enc build on ch==0)
    // --- gemm1: h1c = relu(enc @ w1T[ch*128 ..][:]) ---
    auto stageB1 = [&](int buf, int ks) {
      char* dst = bReg + buf * 24576;
      const short* src0 = w1T + (long)(ch * 128) * 576 + ks * 96;
#pragma unroll
      for (int it = 0; it < 3; ++it) {
        int cw = it * 8 + wave;
        int chk = cw * 64 + lane;
        int rowB = chk / 12, c = chk % 12;
        gl_lds16(src0 + (long)rowB * 576 + swz4(c, rowB) * 8, dst + cw * 1024);
      }
    };
    f32x4 acc1[2][2] = {};
    stageB1(0, 0);
#pragma unroll
    for (int ks = 0; ks < 6; ++ks) {
      __syncthreads();
      if (ks < 5) stageB1((ks & 1) ^ 1, ks + 1);
      const short* Bb = (const short*)(bReg + (ks & 1) * 24576);
      short8 aF[2][3], bF[2][3];
#pragma unroll
      for (int mf = 0; mf < 2; ++mf)
#pragma unroll
        for (int kk = 0; kk < 3; ++kk) {
          int row = wr1 + mf * 16 + fr;
          int c8 = ks * 12 + kk * 4 + fg;
          aF[mf][kk] = *(const short8*)&encS[(row * 72 + swz8(c8, row)) * 8];
        }
#pragma unroll
      for (int nf = 0; nf < 2; ++nf)
#pragma unroll
        for (int kk = 0; kk < 3; ++kk) {
          int col = wc1 + nf * 16 + fr;
          int c = kk * 4 + fg;
          bF[nf][kk] = *(const short8*)&Bb[col * 96 + swz4(c, col) * 8];
        }
#pragma unroll
      for (int kk = 0; kk < 3; ++kk)
#pragma unroll
        for (int mf = 0; mf < 2; ++mf)
#pragma unroll
          for (int nf = 0; nf < 2; ++nf)
            acc1[mf][nf] = MFMA(aF[mf][kk], bF[nf][kk], acc1[mf][nf]);
    }
    // h1c epilogue: relu + bias -> LDS (swizzled); own-tile writes, no race
#pragma unroll
    for (int nf = 0; nf < 2; ++nf) {
      int col = wc1 + nf * 16 + fr;
      float bv = bb1[ch * 128 + col];
#pragma unroll
      for (int mf = 0; mf < 2; ++mf)
#pragma unroll
        for (int i = 0; i < 4; ++i) {
          int row = wr1 + mf * 16 + fg * 4 + i;
          float v = fmaxf(acc1[mf][nf][i] + bv, 0.f);
          h1cS[row * 128 + swz8(col >> 3, row) * 8 + (col & 7)] = f2bf(v);
        }
    }
    __syncthreads();  // h1c visible; B1 reads done -> B region reusable
    // --- gemm2: acc2 += h1c @ w2T[:, ch*128..] ---
    auto stageB2 = [&](int buf, int ks2) {
      char* dst = bReg + buf * 32768;
      const short* src0 = w2T + ch * 128 + ks2 * 32;
#pragma unroll
      for (int it = 0; it < 4; ++it) {
        int cw = it * 8 + wave;
        int chk = cw * 64 + lane;
        int rowB = chk >> 2, c = chk & 3;
        gl_lds16(src0 + (long)rowB * 1024 + swz4(c, rowB) * 8, dst + cw * 1024);
      }
    };
    stageB2(0, 0);
#pragma unroll
    for (int ks2 = 0; ks2 < 4; ++ks2) {
      __syncthreads();
      if (ks2 < 3) stageB2((ks2 & 1) ^ 1, ks2 + 1);
      const short* Bb = (const short*)(bReg + (ks2 & 1) * 32768);
      short8 aF[2], bF[8];
#pragma unroll
      for (int mf = 0; mf < 2; ++mf) {
        int row = wrH + mf * 16 + fr;
        aF[mf] = *(const short8*)&h1cS[row * 128 + swz8(ks2 * 4 + fg, row) * 8];
      }
#pragma unroll
      for (int nf = 0; nf < 8; ++nf) {
        int col = wcH + nf * 16 + fr;
        bF[nf] = *(const short8*)&Bb[col * 32 + swz4(fg, col) * 8];
      }
#pragma unroll
      for (int mf = 0; mf < 2; ++mf)
#pragma unroll
        for (int nf = 0; nf < 8; ++nf)
          acc2[mf][nf] = MFMA(aF[mf], bF[nf], acc2[mf][nf]);
    }
  }
  // ---- h2 write: fp8(relu(acc2 + bb2)) ----
#pragma unroll
  for (int nf = 0; nf < 8; ++nf) {
    int col = wcH + nf * 16 + fr;
    float bv = bb2[col];
#pragma unroll
    for (int mf = 0; mf < 2; ++mf)
#pragma unroll
      for (int i = 0; i < 4; ++i) {
        long row = rb + wrH + mf * 16 + fg * 4 + i;
        h2out[row * 512 + col] = f2fp8(fmaxf(acc2[mf][nf][i] + bv, 0.f));
      }
  }
}

// ============ K2 (64 rows/block): branch(h2@w3, fp8 MFMA) * trunk -> 13-dim out ============
__global__ __launch_bounds__(512)
void k2(const unsigned char* __restrict__ h2, const float* __restrict__ state,
        const float* __restrict__ tw1, const float* __restrict__ tb1,
        const unsigned char* __restrict__ w3f, const float* __restrict__ bb3,
        const short* __restrict__ w4T, const float* __restrict__ tb2,
        const short* __restrict__ pwT, const short* __restrict__ qw1T,
        const short* __restrict__ qw2T, const float* __restrict__ qb1,
        const float* __restrict__ pb, const float* __restrict__ qb2,
        const float* __restrict__ rwp, float* __restrict__ out) {
  __shared__ __align__(16) char lds[114688];
  short* tS  = (short*)lds;              // [64][256] swz8: 32768; later inter
  char*  stg = lds + 32768;              // branch dbuf 2x10240 / trunk dbuf 2x16384
  short* hqS = (short*)(lds + 65536);    // [64][128] swz8: 16384
  short* pwS = (short*)(lds + 81920);    // [16][256] swz8: 8192
  short* q2S = (short*)(lds + 90112);    // [16][128] swz8: 4096
  short* ppS = (short*)(lds + 94208);    // posPad [64][32] swz4: 4096
  short* q1S = (short*)(lds + 98304);    // qw1T [128][32] swz4: 8192
  float* prS = (float*)(lds + 106496);   // [64][16] f32
  float* pr2S= (float*)(lds + 110592);   // [64][16] f32

  const int tid = threadIdx.x, wave = tid >> 6, lane = tid & 63;
  const int fr = lane & 15, fg = lane >> 4;
  const long rb = (long)blockIdx.x * 64;

  // ---- phase 1: stage small weights, build t / posPad ----
  {
    int chk = wave * 64 + lane;
    { int row = chk >> 5, c = chk & 31;
      gl_lds16(pwT + (long)row * 256 + swz8(c, row) * 8, (char*)pwS + wave * 1024); }
    if (wave < 4) { int row = chk >> 4, c = chk & 15;
      gl_lds16(qw2T + (long)row * 128 + swz8(c, row) * 8, (char*)q2S + wave * 1024); }
    { int row = chk >> 2, c = chk & 3;
      gl_lds16(qw1T + (long)row * 32 + swz4(c, row) * 8, (char*)q1S + wave * 1024); }
  }
  for (int i = tid; i < 64 * 32; i += 512) {   // t = tanh(pos @ tw1 + tb1)
    int r = i >> 5, c8 = i & 31;
    float p0 = state[(rb + r) * 13 + 0], p1 = state[(rb + r) * 13 + 1], p2 = state[(rb + r) * 13 + 2];
    short8 v;
#pragma unroll
    for (int j = 0; j < 8; ++j) {
      int jj = c8 * 8 + j;
      v[j] = f2bf(tanhf(p0 * tw1[jj] + p1 * tw1[256 + jj] + p2 * tw1[512 + jj] + tb1[jj]));
    }
    *(short8*)&tS[(r * 32 + swz8(c8, r)) * 8] = v;
  }
  if (tid < 256) {                             // posPad [64][32] bf16
    int r = tid >> 2, c = tid & 3;
    float p0 = state[(rb + r) * 13 + 0], p1 = state[(rb + r) * 13 + 1], p2 = state[(rb + r) * 13 + 2];
    short8 v;
#pragma unroll
    for (int j = 0; j < 8; ++j) {
      int k = c * 8 + j;
      v[j] = (k == 0) ? f2bf(p0) : (k == 1) ? f2bf(p1) : (k == 2) ? f2bf(p2) : (short)0;
    }
    *(short8*)&ppS[(r * 4 + swz4(c, r)) * 8] = v;
  }

  // ---- branch gemm: fp8, K=512, wave tile 64x32 (1M x 8N) ----
  auto stageBr = [&](int buf, int ks) {
    char* d = stg + buf * 10240;
    int ch = wave * 64 + lane;
    if (wave < 2) { int row = ch >> 1, c = (ch & 1) ^ (row & 1);
      gl_lds16(h2 + (rb + row) * 512 + ks * 32 + c * 16, d + wave * 1024); }
    { int row = ch >> 1, c = (ch & 1) ^ (row & 1);
      gl_lds16(w3f + (long)row * 512 + ks * 32 + c * 16, d + 2048 + wave * 1024); }
  };
  f32x4 acc3[4][2] = {};
  stageBr(0, 0);
  __syncthreads();   // phase-1 writes + first stage... (first compute needs stage(0))
#pragma unroll
  for (int ks = 0; ks < 16; ++ks) {
    if (ks) __syncthreads();
    if (ks < 15) stageBr((ks & 1) ^ 1, ks + 1);
    const char* Ab = stg + (ks & 1) * 10240;
    const char* Bb = Ab + 2048;
    long long a[4], b[2];
#pragma unroll
    for (int mf = 0; mf < 4; ++mf) { int row = mf * 16 + fr;
      a[mf] = *(const long long*)(Ab + row * 32 + (((fg >> 1) ^ (row & 1)) << 4) + ((fg & 1) << 3)); }
#pragma unroll
    for (int nf = 0; nf < 2; ++nf) { int col = wave * 32 + nf * 16 + fr;
      b[nf] = *(const long long*)(Bb + col * 32 + (((fg >> 1) ^ (col & 1)) << 4) + ((fg & 1) << 3)); }
#pragma unroll
    for (int mf = 0; mf < 4; ++mf)
#pragma unroll
      for (int nf = 0; nf < 2; ++nf)
        acc3[mf][nf] = MFMA8(a[mf], b[nf], acc3[mf][nf]);
  }
  __syncthreads();  // branch staging reads done -> stg reusable

  // ---- trunk gemm: bf16, K=256, A = tS resident, wave tile 64x32 ----
  auto stageTr = [&](int buf, int ks) {
    char* dst = stg + buf * 16384;
#pragma unroll
    for (int it = 0; it < 2; ++it) {
      int cw = it * 8 + wave;
      int chk = cw * 64 + lane;
      int row = chk >> 2, c = chk & 3;
      gl_lds16(w4T + (long)row * 256 + ks * 32 + swz4(c, row) * 8, dst + cw * 1024);
    }
  };
  f32x4 accT[4][2] = {};
  stageTr(0, 0);
#pragma unroll
  for (int ks = 0; ks < 8; ++ks) {
    __syncthreads();
    if (ks < 7) stageTr((ks & 1) ^ 1, ks + 1);
    const short* Bb = (const short*)(stg + (ks & 1) * 16384);
    short8 aF[4], bF[2];
#pragma unroll
    for (int mf = 0; mf < 4; ++mf) { int row = mf * 16 + fr;
      aF[mf] = *(const short8*)&tS[row * 256 + swz8(ks * 4 + fg, row) * 8]; }
#pragma unroll
    for (int nf = 0; nf < 2; ++nf) { int col = wave * 32 + nf * 16 + fr;
      bF[nf] = *(const short8*)&Bb[col * 32 + swz4(fg, col) * 8]; }
#pragma unroll
    for (int mf = 0; mf < 4; ++mf)
#pragma unroll
      for (int nf = 0; nf < 2; ++nf)
        accT[mf][nf] = MFMA(aF[mf], bF[nf], accT[mf][nf]);
  }
  __syncthreads();  // all tS reads done -> tS reusable as inter

  // ---- interaction -> tS; bias-net hq = relu(posPad @ qw1T + qb1) -> hqS ----
#pragma unroll
  for (int nf = 0; nf < 2; ++nf) {
    int col = wave * 32 + nf * 16 + fr;
    float b3 = bb3[col], t2 = tb2[col];
#pragma unroll
    for (int mf = 0; mf < 4; ++mf)
#pragma unroll
      for (int i = 0; i < 4; ++i) {
        int row = mf * 16 + fg * 4 + i;
        float br = acc3[mf][nf][i] + b3;
        float tr = tanhf(accT[mf][nf][i] + t2);
        tS[row * 256 + swz8(col >> 3, row) * 8 + (col & 7)] = f2bf(br * tr);
      }
  }
  {
    short8 aF[4];
#pragma unroll
    for (int mf = 0; mf < 4; ++mf) { int row = mf * 16 + fr;
      aF[mf] = *(const short8*)&ppS[row * 32 + swz4(fg, row) * 8]; }
    int col = wave * 16 + fr;
    short8 bF = *(const short8*)&q1S[col * 32 + swz4(fg, col) * 8];
    f32x4 aq[4] = {};
#pragma unroll
    for (int mf = 0; mf < 4; ++mf) aq[mf] = MFMA(aF[mf], bF, aq[mf]);
    float qb = qb1[col];
#pragma unroll
    for (int mf = 0; mf < 4; ++mf)
#pragma unroll
      for (int i = 0; i < 4; ++i) {
        int row = mf * 16 + fg * 4 + i;
        float v = fmaxf(aq[mf][i] + qb, 0.f);
        hqS[row * 128 + swz8(col >> 3, row) * 8 + (col & 7)] = f2bf(v);
      }
  }
  __syncthreads();  // inter + hq visible

  // ---- proj: waves 0-3: inter @ pwT (K=256); waves 4-7: hq @ qw2T (K=128) ----
  if (wave < 4) {
    int row = wave * 16 + fr;
    f32x4 accP = {0.f, 0.f, 0.f, 0.f};
#pragma unroll
    for (int ks = 0; ks < 8; ++ks) {
      short8 a = *(const short8*)&tS[row * 256 + swz8(ks * 4 + fg, row) * 8];
      short8 b = *(const short8*)&pwS[fr * 256 + swz8(ks * 4 + fg, fr) * 8];
      accP = MFMA(a, b, accP);
    }
#pragma unroll
    for (int i = 0; i < 4; ++i)
      prS[(wave * 16 + fg * 4 + i) * 16 + fr] = accP[i];
  } else {
    int row = (wave - 4) * 16 + fr;
    f32x4 accQ = {0.f, 0.f, 0.f, 0.f};
#pragma unroll
    for (int ks = 0; ks < 4; ++ks) {
      short8 a = *(const short8*)&hqS[row * 128 + swz8(ks * 4 + fg, row) * 8];
      short8 b = *(const short8*)&q2S[fr * 128 + swz8(ks * 4 + fg, fr) * 8];
      accQ = MFMA(a, b, accQ);
    }
#pragma unroll
    for (int i = 0; i < 4; ++i)
      pr2S[((wave - 4) * 16 + fg * 4 + i) * 16 + fr] = accQ[i];
  }
  __syncthreads();

  // ---- epilogue: residual + quat normalize ----
  if (tid < 64) {
    int r = tid;
    float rw = rwp[0];
    float ns[13];
#pragma unroll
    for (int c = 0; c < 13; ++c)
      ns[c] = state[(rb + r) * 13 + c] + rw * (prS[r * 16 + c] + pr2S[r * 16 + c] + pb[c] + qb2[c]);
    float qn = sqrtf(ns[3] * ns[3] + ns[4] * ns[4] + ns[5] * ns[5] + ns[6] * ns[6]) + 1e-8f;
#pragma unroll
    for (int c = 3; c < 7; ++c) ns[c] /= qn;
#pragma unroll
    for (int c = 0; c < 13; ++c) out[(rb + r) * 13 + c] = ns[c];
  }
}

extern "C" void kernel_launch(void* const* d_in, const int* in_sizes, int n_in,
                              void* d_out, int out_size, void* d_ws, size_t ws_size,
                              hipStream_t stream) {
  const float* state  = (const float*)d_in[0];
  const float* action = (const float*)d_in[1];
  const float* sensors= (const float*)d_in[2];
  const float* bw1 = (const float*)d_in[3];
  const float* bb1 = (const float*)d_in[4];
  const float* bw2 = (const float*)d_in[5];
  const float* bb2 = (const float*)d_in[6];
  const float* bw3 = (const float*)d_in[7];
  const float* bb3 = (const float*)d_in[8];
  const float* tw1 = (const float*)d_in[9];
  const float* tb1 = (const float*)d_in[10];
  const float* tw2 = (const float*)d_in[11];
  const float* tb2 = (const float*)d_in[12];
  const float* qw1 = (const float*)d_in[13];
  const float* qb1 = (const float*)d_in[14];
  const float* qw2 = (const float*)d_in[15];
  const float* qb2 = (const float*)d_in[16];
  const float* pw  = (const float*)d_in[17];
  const float* pb  = (const float*)d_in[18];
  const float* rw  = (const float*)d_in[19];
  float* out = (float*)d_out;

  char* p = (char*)d_ws;
  short* w1T = (short*)p; p += (size_t)1024 * 576 * 2;
  short* w2T = (short*)p; p += (size_t)512 * 1024 * 2;
  unsigned char* w3f = (unsigned char*)p; p += (size_t)256 * 512;
  short* w4T = (short*)p; p += (size_t)256 * 256 * 2;
  short* pwT = (short*)p; p += (size_t)16 * 256 * 2;
  short* qw1T= (short*)p; p += (size_t)128 * 32 * 2;
  short* qw2T= (short*)p; p += (size_t)16 * 128 * 2;
  const size_t fixed = (size_t)(p - (char*)d_ws);
  const size_t avail = (ws_size > fixed) ? ws_size - fixed : 0;
  long Mc = (long)(avail / 512) & ~255L;   // h2 chunk: 512 fp8 bytes per row
  if (Mc > 16384) Mc = 16384;              // 16384 rows -> 256 blocks for both k1,k2
  if (Mc < 256) return;
  unsigned char* h2b = (unsigned char*)p;

  conv_wT<<<dim3(2304), dim3(256), 0, stream>>>(bw1, w1T, 544, 1024, 576);
  conv_wT<<<dim3(2048), dim3(256), 0, stream>>>(bw2, w2T, 1024, 512, 1024);
  conv_w3f8<<<dim3(512), dim3(256), 0, stream>>>(bw3, w3f);
  conv_wT<<<dim3(256),  dim3(256), 0, stream>>>(tw2, w4T, 256, 256, 256);
  conv_small<<<dim3(40), dim3(256), 0, stream>>>(pw, qw1, qw2, pwT, qw1T, qw2T);

  for (long r0 = 0; r0 < B_TOTAL; r0 += Mc) {
    long Mr = B_TOTAL - r0; if (Mr > Mc) Mr = Mc;
    k1<<<dim3(Mr / 64), dim3(512), 0, stream>>>(state + r0 * 13, action + r0 * 4, sensors,
                                                w1T, bb1, w2T, bb2, h2b);
    k2<<<dim3(Mr / 64), dim3(512), 0, stream>>>(h2b, state + r0 * 13, tw1, tb1,
                                                w3f, bb3, w4T, tb2, pwT, qw1T, qw2T,
                                                qb1, pb, qb2, rw, out + r0 * 13);
  }
}

// Round 4
// 703.516 us; speedup vs baseline: 1.0519x; 1.0519x over previous
//
#include <hip/hip_runtime.h>
#include <hip/hip_bf16.h>
#include <hip/hip_fp8.h>

#define B_TOTAL 131072

typedef __attribute__((ext_vector_type(8))) short short8;   // 8 bf16 MFMA A/B frag
typedef __attribute__((ext_vector_type(4))) float f32x4;    // MFMA C/D frag
typedef unsigned int uint;

#define MFMA(a,b,c) __builtin_amdgcn_mfma_f32_16x16x32_bf16(a,b,c,0,0,0)
#define MFMA8(a,b,c) __builtin_amdgcn_mfma_f32_16x16x32_fp8_fp8(a,b,c,0,0,0)

__device__ __forceinline__ short f2bf(float f) {
  union { float f; uint u; } x; x.f = f;
  uint r = x.u + 0x7fffu + ((x.u >> 16) & 1u);  // RTNE
  return (short)(r >> 16);
}
__device__ __forceinline__ unsigned char f2fp8(float v) {
  union { __hip_fp8_e4m3 q; unsigned char b; } u;
  u.q = __hip_fp8_e4m3(v);
  return u.b;
}

__device__ __forceinline__ void gl_lds16(const void* g, void* l) {
  __builtin_amdgcn_global_load_lds((const __attribute__((address_space(1))) uint*)g,
                                   (__attribute__((address_space(3))) uint*)l, 16, 0, 0);
}
// 16B-chunk swizzles (writer & reader use the same involution)
__device__ __forceinline__ int swz4(int c, int r) { return (c & ~3) | ((c ^ r ^ (r >> 2)) & 3); }
__device__ __forceinline__ int swz8(int c, int r) { return (c & ~7) | ((c ^ r) & 7); }

// ---- weight convert+transpose: w[K][N] f32 -> wt[N][Kpad] bf16 (zero pad) ----
__global__ void conv_wT(const float* __restrict__ w, short* __restrict__ wt,
                        int K, int N, int Kpad) {
  const int i = blockIdx.x * 256 + threadIdx.x;
  if (i >= N * Kpad) return;
  const int n = i / Kpad, k = i % Kpad;
  wt[(long)n * Kpad + k] = (k < K) ? f2bf(w[(long)k * N + n]) : (short)0;
}

// ---- w3 [512][256] f32 -> w3f [256 n][512 k] fp8 ----
__global__ void conv_w3f8(const float* __restrict__ w, unsigned char* __restrict__ wt) {
  const int i = blockIdx.x * 256 + threadIdx.x;
  if (i >= 256 * 512) return;
  const int n = i >> 9, k = i & 511;
  wt[i] = f2fp8(w[k * 256 + n]);
}

// ---- small weights: pwT[16][256], qw1T[128][32], qw2T[16][128] (zero-padded) ----
__global__ void conv_small(const float* __restrict__ pw, const float* __restrict__ qw1,
                           const float* __restrict__ qw2, short* __restrict__ pwT,
                           short* __restrict__ qw1T, short* __restrict__ qw2T) {
  int t = blockIdx.x * 256 + threadIdx.x;
  if (t < 4096) { int c = t >> 8, k = t & 255; pwT[t] = (c < 13) ? f2bf(pw[k * 13 + c]) : (short)0; }
  else if (t < 8192) { int i = t - 4096; int j = i >> 5, k = i & 31;
    qw1T[i] = (k < 3) ? f2bf(qw1[k * 128 + j]) : (short)0; }
  else if (t < 10240) { int i = t - 8192; int c = i >> 7, j = i & 127;
    qw2T[i] = (c < 13) ? f2bf(qw2[j * 13 + c]) : (short)0; }
}

// ---- enc kernel: builds enc[M][576] bf16 (zero-padded cols 544..575) ----
__global__ __launch_bounds__(256)
void enc_k(const float* __restrict__ state, const float* __restrict__ action,
           const float* __restrict__ sensors, short* __restrict__ enc) {
  __shared__ float sval[64][17];
  __shared__ float wexp[64][32];
  __shared__ float sens[96];
  const int tid = threadIdx.x;
  const int rb = blockIdx.x * 64;
  if (tid < 96) sens[tid] = sensors[tid];
  for (int i = tid; i < 64 * 17; i += 256) {
    const int r = i / 17, c = i % 17;
    const long grow = rb + r;
    sval[r][c] = (c < 13) ? state[grow * 13 + c] : action[grow * 4 + (c - 13)];
  }
  __syncthreads();
  for (int i = tid; i < 64 * 32; i += 256) {
    const int r = i >> 5, s = i & 31;
    const float dx = sens[s*3+0] - sval[r][0];
    const float dy = sens[s*3+1] - sval[r][1];
    const float dz = sens[s*3+2] - sval[r][2];
    wexp[r][s] = __expf(-2.0f * sqrtf(dx*dx + dy*dy + dz*dz));
  }
  __syncthreads();
  for (int i = tid; i < 64 * 72; i += 256) {
    const int r = i / 72, c8 = i % 72;
    short8 v;
#pragma unroll
    for (int j = 0; j < 8; ++j) {
      const int k = c8 * 8 + j;
      float f = 0.f;
      if (k < 544) { const int s = k / 17, c = k % 17; f = sval[r][c] * wexp[r][s]; }
      v[j] = f2bf(f);
    }
    *(short8*)&enc[((long)(rb + r)) * 576 + c8 * 8] = v;
  }
}

// ---- GEMM (round-1 proven): C[M][N] = act(A @ Bt^T + bias), 128x128 tile, 4 waves ----
// ACT: 0 none, 1 relu. OUT8: write fp8 e4m3 instead of bf16.
template<int N, int K, int LDA, int ACT, int OUT8>
__global__ __launch_bounds__(256, 2)
void gemm_bt(const short* __restrict__ A, const short* __restrict__ Bt,
             const float* __restrict__ bias, void* __restrict__ Cv) {
  constexpr int NT = K / 64;
  constexpr int NTN = N / 128;
  __shared__ __align__(16) short As[2][128 * 64];
  __shared__ __align__(16) short Bs[2][128 * 64];
  const int tid = threadIdx.x;
  const int wave = tid >> 6;
  const int lane = tid & 63;
  const int tm = blockIdx.x / NTN;
  const int tn = blockIdx.x % NTN;
  const long arow0 = (long)tm * 128;
  const long brow0 = (long)tn * 128;

  auto stage = [&](int b, int kt) {
    const int k0 = kt * 64;
#pragma unroll
    for (int it = 0; it < 4; ++it) {
      const int cw = it * 4 + wave;        // 16 wave-calls of 1KB each
      const int ch = cw * 64 + lane;       // chunk id (16B) 0..1023
      const int row = ch >> 3;
      const int cs = (ch & 7) ^ (row & 7); // inverse-swizzled source chunk
      gl_lds16(A + (arow0 + row) * (long)LDA + (k0 + cs * 8), &As[b][cw * 512]);
      gl_lds16(Bt + (brow0 + row) * (long)K + (k0 + cs * 8), &Bs[b][cw * 512]);
    }
  };

  const int wr = (wave >> 1) * 64;
  const int wc = (wave & 1) * 64;
  const int fr = lane & 15;
  const int fg = lane >> 4;

  f32x4 acc[4][4] = {};

  stage(0, 0);
  for (int kt = 0; kt < NT; ++kt) {
    const int cur = kt & 1;
    __syncthreads();
    if (kt + 1 < NT) stage(cur ^ 1, kt + 1);
    const short* Ab = As[cur];
    const short* Bb = Bs[cur];
    short8 af[4][2], bfr[4][2];
#pragma unroll
    for (int m = 0; m < 4; ++m)
#pragma unroll
      for (int kk = 0; kk < 2; ++kk) {
        const int row = wr + m * 16 + fr;
        const int c = kk * 4 + fg;
        af[m][kk] = *(const short8*)&Ab[row * 64 + ((c ^ (row & 7)) * 8)];
      }
#pragma unroll
    for (int n = 0; n < 4; ++n)
#pragma unroll
      for (int kk = 0; kk < 2; ++kk) {
        const int col = wc + n * 16 + fr;
        const int c = kk * 4 + fg;
        bfr[n][kk] = *(const short8*)&Bb[col * 64 + ((c ^ (col & 7)) * 8)];
      }
#pragma unroll
    for (int kk = 0; kk < 2; ++kk)
#pragma unroll
      for (int m = 0; m < 4; ++m)
#pragma unroll
        for (int n = 0; n < 4; ++n)
          acc[m][n] = MFMA(af[m][kk], bfr[n][kk], acc[m][n]);
  }

  float bv[4];
#pragma unroll
  for (int n = 0; n < 4; ++n) bv[n] = bias[tn * 128 + wc + n * 16 + fr];
#pragma unroll
  for (int m = 0; m < 4; ++m)
#pragma unroll
    for (int n = 0; n < 4; ++n) {
      const long col = brow0 + wc + n * 16 + fr;
#pragma unroll
      for (int r = 0; r < 4; ++r) {
        const long row = arow0 + wr + m * 16 + fg * 4 + r;  // m89-verified C/D layout
        float v = acc[m][n][r] + bv[n];
        if (ACT == 1) v = fmaxf(v, 0.f);
        if (OUT8) ((unsigned char*)Cv)[row * (long)N + col] = f2fp8(v);
        else      ((short*)Cv)[row * (long)N + col] = f2bf(v);
      }
    }
}

// ============ K2 (64 rows/block): branch(h2@w3, fp8 MFMA) * trunk -> 13-dim out ============
__global__ __launch_bounds__(512)
void k2(const unsigned char* __restrict__ h2, const float* __restrict__ state,
        const float* __restrict__ tw1, const float* __restrict__ tb1,
        const unsigned char* __restrict__ w3f, const float* __restrict__ bb3,
        const short* __restrict__ w4T, const float* __restrict__ tb2,
        const short* __restrict__ pwT, const short* __restrict__ qw1T,
        const short* __restrict__ qw2T, const float* __restrict__ qb1,
        const float* __restrict__ pb, const float* __restrict__ qb2,
        const float* __restrict__ rwp, float* __restrict__ out) {
  __shared__ __align__(16) char lds[114688];
  short* tS  = (short*)lds;              // [64][256] swz8: 32768; later inter
  char*  stg = lds + 32768;              // branch dbuf 2x10240 / trunk dbuf 2x16384
  short* hqS = (short*)(lds + 65536);    // [64][128] swz8: 16384
  short* pwS = (short*)(lds + 81920);    // [16][256] swz8: 8192
  short* q2S = (short*)(lds + 90112);    // [16][128] swz8: 4096
  short* ppS = (short*)(lds + 94208);    // posPad [64][32] swz4: 4096
  short* q1S = (short*)(lds + 98304);    // qw1T [128][32] swz4: 8192
  float* prS = (float*)(lds + 106496);   // [64][16] f32
  float* pr2S= (float*)(lds + 110592);   // [64][16] f32

  const int tid = threadIdx.x, wave = tid >> 6, lane = tid & 63;
  const int fr = lane & 15, fg = lane >> 4;
  const long rb = (long)blockIdx.x * 64;

  // ---- phase 1: stage small weights, build t / posPad ----
  {
    int chk = wave * 64 + lane;
    { int row = chk >> 5, c = chk & 31;
      gl_lds16(pwT + (long)row * 256 + swz8(c, row) * 8, (char*)pwS + wave * 1024); }
    if (wave < 4) { int row = chk >> 4, c = chk & 15;
      gl_lds16(qw2T + (long)row * 128 + swz8(c, row) * 8, (char*)q2S + wave * 1024); }
    { int row = chk >> 2, c = chk & 3;
      gl_lds16(qw1T + (long)row * 32 + swz4(c, row) * 8, (char*)q1S + wave * 1024); }
  }
  for (int i = tid; i < 64 * 32; i += 512) {   // t = tanh(pos @ tw1 + tb1)
    int r = i >> 5, c8 = i & 31;
    float p0 = state[(rb + r) * 13 + 0], p1 = state[(rb + r) * 13 + 1], p2 = state[(rb + r) * 13 + 2];
    short8 v;
#pragma unroll
    for (int j = 0; j < 8; ++j) {
      int jj = c8 * 8 + j;
      v[j] = f2bf(tanhf(p0 * tw1[jj] + p1 * tw1[256 + jj] + p2 * tw1[512 + jj] + tb1[jj]));
    }
    *(short8*)&tS[(r * 32 + swz8(c8, r)) * 8] = v;
  }
  if (tid < 256) {                             // posPad [64][32] bf16
    int r = tid >> 2, c = tid & 3;
    float p0 = state[(rb + r) * 13 + 0], p1 = state[(rb + r) * 13 + 1], p2 = state[(rb + r) * 13 + 2];
    short8 v;
#pragma unroll
    for (int j = 0; j < 8; ++j) {
      int k = c * 8 + j;
      v[j] = (k == 0) ? f2bf(p0) : (k == 1) ? f2bf(p1) : (k == 2) ? f2bf(p2) : (short)0;
    }
    *(short8*)&ppS[(r * 4 + swz4(c, r)) * 8] = v;
  }

  // ---- branch gemm: fp8, K=512, wave tile 64x32 (1M x 8N) ----
  auto stageBr = [&](int buf, int ks) {
    char* d = stg + buf * 10240;
    int ch = wave * 64 + lane;
    if (wave < 2) { int row = ch >> 1, c = (ch & 1) ^ (row & 1);
      gl_lds16(h2 + (rb + row) * 512 + ks * 32 + c * 16, d + wave * 1024); }
    { int row = ch >> 1, c = (ch & 1) ^ (row & 1);
      gl_lds16(w3f + (long)row * 512 + ks * 32 + c * 16, d + 2048 + wave * 1024); }
  };
  f32x4 acc3[4][2] = {};
  stageBr(0, 0);
  __syncthreads();
#pragma unroll
  for (int ks = 0; ks < 16; ++ks) {
    if (ks) __syncthreads();
    if (ks < 15) stageBr((ks & 1) ^ 1, ks + 1);
    const char* Ab = stg + (ks & 1) * 10240;
    const char* Bb = Ab + 2048;
    long long a[4], b[2];
#pragma unroll
    for (int mf = 0; mf < 4; ++mf) { int row = mf * 16 + fr;
      a[mf] = *(const long long*)(Ab + row * 32 + (((fg >> 1) ^ (row & 1)) << 4) + ((fg & 1) << 3)); }
#pragma unroll
    for (int nf = 0; nf < 2; ++nf) { int col = wave * 32 + nf * 16 + fr;
      b[nf] = *(const long long*)(Bb + col * 32 + (((fg >> 1) ^ (col & 1)) << 4) + ((fg & 1) << 3)); }
#pragma unroll
    for (int mf = 0; mf < 4; ++mf)
#pragma unroll
      for (int nf = 0; nf < 2; ++nf)
        acc3[mf][nf] = MFMA8(a[mf], b[nf], acc3[mf][nf]);
  }
  __syncthreads();  // branch staging reads done -> stg reusable

  // ---- trunk gemm: bf16, K=256, A = tS resident, wave tile 64x32 ----
  auto stageTr = [&](int buf, int ks) {
    char* dst = stg + buf * 16384;
#pragma unroll
    for (int it = 0; it < 2; ++it) {
      int cw = it * 8 + wave;
      int chk = cw * 64 + lane;
      int row = chk >> 2, c = chk & 3;
      gl_lds16(w4T + (long)row * 256 + ks * 32 + swz4(c, row) * 8, dst + cw * 1024);
    }
  };
  f32x4 accT[4][2] = {};
  stageTr(0, 0);
#pragma unroll
  for (int ks = 0; ks < 8; ++ks) {
    __syncthreads();
    if (ks < 7) stageTr((ks & 1) ^ 1, ks + 1);
    const short* Bb = (const short*)(stg + (ks & 1) * 16384);
    short8 aF[4], bF[2];
#pragma unroll
    for (int mf = 0; mf < 4; ++mf) { int row = mf * 16 + fr;
      aF[mf] = *(const short8*)&tS[row * 256 + swz8(ks * 4 + fg, row) * 8]; }
#pragma unroll
    for (int nf = 0; nf < 2; ++nf) { int col = wave * 32 + nf * 16 + fr;
      bF[nf] = *(const short8*)&Bb[col * 32 + swz4(fg, col) * 8]; }
#pragma unroll
    for (int mf = 0; mf < 4; ++mf)
#pragma unroll
      for (int nf = 0; nf < 2; ++nf)
        accT[mf][nf] = MFMA(aF[mf], bF[nf], accT[mf][nf]);
  }
  __syncthreads();  // all tS reads done -> tS reusable as inter

  // ---- interaction -> tS; bias-net hq = relu(posPad @ qw1T + qb1) -> hqS ----
#pragma unroll
  for (int nf = 0; nf < 2; ++nf) {
    int col = wave * 32 + nf * 16 + fr;
    float b3 = bb3[col], t2 = tb2[col];
#pragma unroll
    for (int mf = 0; mf < 4; ++mf)
#pragma unroll
      for (int i = 0; i < 4; ++i) {
        int row = mf * 16 + fg * 4 + i;
        float br = acc3[mf][nf][i] + b3;
        float tr = tanhf(accT[mf][nf][i] + t2);
        tS[row * 256 + swz8(col >> 3, row) * 8 + (col & 7)] = f2bf(br * tr);
      }
  }
  {
    short8 aF[4];
#pragma unroll
    for (int mf = 0; mf < 4; ++mf) { int row = mf * 16 + fr;
      aF[mf] = *(const short8*)&ppS[row * 32 + swz4(fg, row) * 8]; }
    int col = wave * 16 + fr;
    short8 bF = *(const short8*)&q1S[col * 32 + swz4(fg, col) * 8];
    f32x4 aq[4] = {};
#pragma unroll
    for (int mf = 0; mf < 4; ++mf) aq[mf] = MFMA(aF[mf], bF, aq[mf]);
    float qb = qb1[col];
#pragma unroll
    for (int mf = 0; mf < 4; ++mf)
#pragma unroll
      for (int i = 0; i < 4; ++i) {
        int row = mf * 16 + fg * 4 + i;
        float v = fmaxf(aq[mf][i] + qb, 0.f);
        hqS[row * 128 + swz8(col >> 3, row) * 8 + (col & 7)] = f2bf(v);
      }
  }
  __syncthreads();  // inter + hq visible

  // ---- proj: waves 0-3: inter @ pwT (K=256); waves 4-7: hq @ qw2T (K=128) ----
  if (wave < 4) {
    int row = wave * 16 + fr;
    f32x4 accP = {0.f, 0.f, 0.f, 0.f};
#pragma unroll
    for (int ks = 0; ks < 8; ++ks) {
      short8 a = *(const short8*)&tS[row * 256 + swz8(ks * 4 + fg, row) * 8];
      short8 b = *(const short8*)&pwS[fr * 256 + swz8(ks * 4 + fg, fr) * 8];
      accP = MFMA(a, b, accP);
    }
#pragma unroll
    for (int i = 0; i < 4; ++i)
      prS[(wave * 16 + fg * 4 + i) * 16 + fr] = accP[i];
  } else {
    int row = (wave - 4) * 16 + fr;
    f32x4 accQ = {0.f, 0.f, 0.f, 0.f};
#pragma unroll
    for (int ks = 0; ks < 4; ++ks) {
      short8 a = *(const short8*)&hqS[row * 128 + swz8(ks * 4 + fg, row) * 8];
      short8 b = *(const short8*)&q2S[fr * 128 + swz8(ks * 4 + fg, fr) * 8];
      accQ = MFMA(a, b, accQ);
    }
#pragma unroll
    for (int i = 0; i < 4; ++i)
      pr2S[((wave - 4) * 16 + fg * 4 + i) * 16 + fr] = accQ[i];
  }
  __syncthreads();

  // ---- epilogue: residual + quat normalize ----
  if (tid < 64) {
    int r = tid;
    float rw = rwp[0];
    float ns[13];
#pragma unroll
    for (int c = 0; c < 13; ++c)
      ns[c] = state[(rb + r) * 13 + c] + rw * (prS[r * 16 + c] + pr2S[r * 16 + c] + pb[c] + qb2[c]);
    float qn = sqrtf(ns[3] * ns[3] + ns[4] * ns[4] + ns[5] * ns[5] + ns[6] * ns[6]) + 1e-8f;
#pragma unroll
    for (int c = 3; c < 7; ++c) ns[c] /= qn;
#pragma unroll
    for (int c = 0; c < 13; ++c) out[(rb + r) * 13 + c] = ns[c];
  }
}

extern "C" void kernel_launch(void* const* d_in, const int* in_sizes, int n_in,
                              void* d_out, int out_size, void* d_ws, size_t ws_size,
                              hipStream_t stream) {
  const float* state  = (const float*)d_in[0];
  const float* action = (const float*)d_in[1];
  const float* sensors= (const float*)d_in[2];
  const float* bw1 = (const float*)d_in[3];
  const float* bb1 = (const float*)d_in[4];
  const float* bw2 = (const float*)d_in[5];
  const float* bb2 = (const float*)d_in[6];
  const float* bw3 = (const float*)d_in[7];
  const float* bb3 = (const float*)d_in[8];
  const float* tw1 = (const float*)d_in[9];
  const float* tb1 = (const float*)d_in[10];
  const float* tw2 = (const float*)d_in[11];
  const float* tb2 = (const float*)d_in[12];
  const float* qw1 = (const float*)d_in[13];
  const float* qb1 = (const float*)d_in[14];
  const float* qw2 = (const float*)d_in[15];
  const float* qb2 = (const float*)d_in[16];
  const float* pw  = (const float*)d_in[17];
  const float* pb  = (const float*)d_in[18];
  const float* rw  = (const float*)d_in[19];
  float* out = (float*)d_out;

  char* p = (char*)d_ws;
  short* w1T = (short*)p; p += (size_t)1024 * 576 * 2;
  short* w2T = (short*)p; p += (size_t)512 * 1024 * 2;
  unsigned char* w3f = (unsigned char*)p; p += (size_t)256 * 512;
  short* w4T = (short*)p; p += (size_t)256 * 256 * 2;
  short* pwT = (short*)p; p += (size_t)16 * 256 * 2;
  short* qw1T= (short*)p; p += (size_t)128 * 32 * 2;
  short* qw2T= (short*)p; p += (size_t)16 * 128 * 2;
  const size_t fixed = (size_t)(p - (char*)d_ws);
  const size_t avail = (ws_size > fixed) ? ws_size - fixed : 0;
  // per-row: enc 576*2 (h2 fp8 512B overlaid after gemm1) + h1 1024*2
  long Mc = (long)(avail / 3200) & ~255L;
  if (Mc > B_TOTAL) Mc = B_TOTAL;
  if (Mc < 256) return;
  short* encb = (short*)p;                         // Mc*576 bf16; h2 fp8 overlays
  unsigned char* h2b = (unsigned char*)p;
  short* h1b = (short*)(p + (size_t)Mc * 1152);    // Mc*1024 bf16

  conv_wT<<<dim3(2304), dim3(256), 0, stream>>>(bw1, w1T, 544, 1024, 576);
  conv_wT<<<dim3(2048), dim3(256), 0, stream>>>(bw2, w2T, 1024, 512, 1024);
  conv_w3f8<<<dim3(512), dim3(256), 0, stream>>>(bw3, w3f);
  conv_wT<<<dim3(256),  dim3(256), 0, stream>>>(tw2, w4T, 256, 256, 256);
  conv_small<<<dim3(40), dim3(256), 0, stream>>>(pw, qw1, qw2, pwT, qw1T, qw2T);

  for (long r0 = 0; r0 < B_TOTAL; r0 += Mc) {
    long Mr = B_TOTAL - r0; if (Mr > Mc) Mr = Mc;
    enc_k<<<dim3(Mr / 64), dim3(256), 0, stream>>>(state + r0 * 13, action + r0 * 4,
                                                   sensors, encb);
    gemm_bt<1024, 576, 576, 1, 0><<<dim3((Mr / 128) * 8), dim3(256), 0, stream>>>(
        encb, w1T, bb1, h1b);
    gemm_bt<512, 1024, 1024, 1, 1><<<dim3((Mr / 128) * 4), dim3(256), 0, stream>>>(
        h1b, w2T, bb2, h2b);
    k2<<<dim3(Mr / 64), dim3(512), 0, stream>>>(h2b, state + r0 * 13, tw1, tb1,
                                                w3f, bb3, w4T, tb2, pwT, qw1T, qw2T,
                                                qb1, pb, qb2, rw, out + r0 * 13);
  }
}

// Round 5
// 588.361 us; speedup vs baseline: 1.2578x; 1.1957x over previous
//
#include <hip/hip_runtime.h>
#include <hip/hip_bf16.h>
#include <hip/hip_fp8.h>

#define B_TOTAL 131072

typedef __attribute__((ext_vector_type(8))) short short8;   // 8 bf16 MFMA A/B frag
typedef __attribute__((ext_vector_type(4))) float f32x4;    // MFMA C/D frag
typedef unsigned int uint;

#define MFMA(a,b,c) __builtin_amdgcn_mfma_f32_16x16x32_bf16(a,b,c,0,0,0)
#define MFMA8(a,b,c) __builtin_amdgcn_mfma_f32_16x16x32_fp8_fp8(a,b,c,0,0,0)

__device__ __forceinline__ short f2bf(float f) {
  union { float f; uint u; } x; x.f = f;
  uint r = x.u + 0x7fffu + ((x.u >> 16) & 1u);  // RTNE
  return (short)(r >> 16);
}
__device__ __forceinline__ unsigned char f2fp8(float v) {
  union { __hip_fp8_e4m3 q; unsigned char b; } u;
  u.q = __hip_fp8_e4m3(v);
  return u.b;
}

__device__ __forceinline__ void gl_lds16(const void* g, void* l) {
  __builtin_amdgcn_global_load_lds((const __attribute__((address_space(1))) uint*)g,
                                   (__attribute__((address_space(3))) uint*)l, 16, 0, 0);
}
// 16B-chunk swizzles (writer & reader use the same involution)
__device__ __forceinline__ int swz4(int c, int r) { return (c & ~3) | ((c ^ r ^ (r >> 2)) & 3); }
__device__ __forceinline__ int swz8(int c, int r) { return (c & ~7) | ((c ^ r) & 7); }

// ============ merged weight prep: LDS-tiled transpose, coalesced both sides ============
// w1T[1024][576] bf16 | w2f[512][1024] fp8 | w3f[256][512] fp8 | w4T[256][256] bf16 | smalls
__global__ __launch_bounds__(256)
void prep(const float* __restrict__ bw1, const float* __restrict__ bw2,
          const float* __restrict__ bw3, const float* __restrict__ tw2,
          const float* __restrict__ pw, const float* __restrict__ qw1,
          const float* __restrict__ qw2,
          short* __restrict__ w1T, unsigned char* __restrict__ w2f,
          unsigned char* __restrict__ w3f, short* __restrict__ w4T,
          short* __restrict__ pwT, short* __restrict__ qw1T, short* __restrict__ qw2T) {
  __shared__ float tile[32][33];
  int b = blockIdx.x;
  if (b == 1280) {  // small weights, scattered (tiny)
    for (int t = threadIdx.x; t < 10240; t += 256) {
      if (t < 4096) { int c = t >> 8, k = t & 255;
        pwT[t] = (c < 13) ? f2bf(pw[k * 13 + c]) : (short)0; }
      else if (t < 8192) { int i = t - 4096; int j = i >> 5, k = i & 31;
        qw1T[i] = (k < 3) ? f2bf(qw1[k * 128 + j]) : (short)0; }
      else { int i = t - 8192; int c = i >> 7, j = i & 127;
        qw2T[i] = (c < 13) ? f2bf(qw2[j * 13 + c]) : (short)0; }
    }
    return;
  }
  const float* src; void* dst; int K, N, Kpad, ntk, dt8;
  if (b < 576)       { src = bw1; dst = w1T; K = 544;  N = 1024; Kpad = 576;  ntk = 18; dt8 = 0; }
  else if (b < 1088) { b -= 576;  src = bw2; dst = w2f; K = 1024; N = 512;  Kpad = 1024; ntk = 32; dt8 = 1; }
  else if (b < 1216) { b -= 1088; src = bw3; dst = w3f; K = 512;  N = 256;  Kpad = 512;  ntk = 16; dt8 = 1; }
  else               { b -= 1216; src = tw2; dst = w4T; K = 256;  N = 256;  Kpad = 256;  ntk = 8;  dt8 = 0; }
  const int tn = b / ntk, tk = b % ntk;
  const int k0 = tk * 32, n0 = tn * 32;
  const int tx = threadIdx.x & 31, ty = threadIdx.x >> 5;
#pragma unroll
  for (int rr = 0; rr < 32; rr += 8) {
    int k = k0 + ty + rr;
    tile[ty + rr][tx] = (k < K) ? src[(long)k * N + n0 + tx] : 0.f;
  }
  __syncthreads();
#pragma unroll
  for (int rr = 0; rr < 32; rr += 8) {
    int nl = ty + rr;
    float v = tile[tx][nl];
    if (dt8) ((unsigned char*)dst)[(long)(n0 + nl) * Kpad + k0 + tx] = f2fp8(v);
    else     ((short*)dst)[(long)(n0 + nl) * Kpad + k0 + tx] = f2bf(v);
  }
}

// ---- enc kernel: builds enc[M][576] bf16 (zero-padded cols 544..575) ----
__global__ __launch_bounds__(256)
void enc_k(const float* __restrict__ state, const float* __restrict__ action,
           const float* __restrict__ sensors, short* __restrict__ enc) {
  __shared__ float sval[64][17];
  __shared__ float wexp[64][32];
  __shared__ float sens[96];
  const int tid = threadIdx.x;
  const int rb = blockIdx.x * 64;
  if (tid < 96) sens[tid] = sensors[tid];
  for (int i = tid; i < 64 * 17; i += 256) {
    const int r = i / 17, c = i % 17;
    const long grow = rb + r;
    sval[r][c] = (c < 13) ? state[grow * 13 + c] : action[grow * 4 + (c - 13)];
  }
  __syncthreads();
  for (int i = tid; i < 64 * 32; i += 256) {
    const int r = i >> 5, s = i & 31;
    const float dx = sens[s*3+0] - sval[r][0];
    const float dy = sens[s*3+1] - sval[r][1];
    const float dz = sens[s*3+2] - sval[r][2];
    wexp[r][s] = __expf(-2.0f * sqrtf(dx*dx + dy*dy + dz*dz));
  }
  __syncthreads();
  for (int i = tid; i < 64 * 72; i += 256) {
    const int r = i / 72, c8 = i % 72;
    short8 v;
#pragma unroll
    for (int j = 0; j < 8; ++j) {
      const int k = c8 * 8 + j;
      float f = 0.f;
      if (k < 544) { const int s = k / 17, c = k % 17; f = sval[r][c] * wexp[r][s]; }
      v[j] = f2bf(f);
    }
    *(short8*)&enc[((long)(rb + r)) * 576 + c8 * 8] = v;
  }
}

// ---- GEMM bf16 (proven structure) + XCD-aware tm/tn remap. OUT8: fp8 output ----
template<int N, int K, int LDA, int ACT, int OUT8>
__global__ __launch_bounds__(256, 2)
void gemm_bt(const short* __restrict__ A, const short* __restrict__ Bt,
             const float* __restrict__ bias, void* __restrict__ Cv) {
  constexpr int NT = K / 64;
  constexpr int NTN = N / 128;
  __shared__ __align__(16) short As[2][128 * 64];
  __shared__ __align__(16) short Bs[2][128 * 64];
  const int tid = threadIdx.x;
  const int wave = tid >> 6;
  const int lane = tid & 63;
  // XCD-aware remap: all NTN blocks of one tm land on one XCD, adjacent in time.
  const int Mtiles = gridDim.x / NTN;          // must be multiple of 8
  const int bid = blockIdx.x;
  const int xcd = bid & 7, seq = bid >> 3;
  const int tm = xcd * (Mtiles >> 3) + seq / NTN;
  const int tn = seq % NTN;
  const long arow0 = (long)tm * 128;
  const long brow0 = (long)tn * 128;

  auto stage = [&](int b, int kt) {
    const int k0 = kt * 64;
#pragma unroll
    for (int it = 0; it < 4; ++it) {
      const int cw = it * 4 + wave;
      const int ch = cw * 64 + lane;       // 16B chunk id 0..1023
      const int row = ch >> 3;
      const int cs = (ch & 7) ^ (row & 7); // inverse-swizzled source chunk
      gl_lds16(A + (arow0 + row) * (long)LDA + (k0 + cs * 8), &As[b][cw * 512]);
      gl_lds16(Bt + (brow0 + row) * (long)K + (k0 + cs * 8), &Bs[b][cw * 512]);
    }
  };

  const int wr = (wave >> 1) * 64;
  const int wc = (wave & 1) * 64;
  const int fr = lane & 15;
  const int fg = lane >> 4;

  f32x4 acc[4][4] = {};

  stage(0, 0);
  for (int kt = 0; kt < NT; ++kt) {
    const int cur = kt & 1;
    __syncthreads();
    if (kt + 1 < NT) stage(cur ^ 1, kt + 1);
    const short* Ab = As[cur];
    const short* Bb = Bs[cur];
    short8 af[4][2], bfr[4][2];
#pragma unroll
    for (int m = 0; m < 4; ++m)
#pragma unroll
      for (int kk = 0; kk < 2; ++kk) {
        const int row = wr + m * 16 + fr;
        const int c = kk * 4 + fg;
        af[m][kk] = *(const short8*)&Ab[row * 64 + ((c ^ (row & 7)) * 8)];
      }
#pragma unroll
    for (int n = 0; n < 4; ++n)
#pragma unroll
      for (int kk = 0; kk < 2; ++kk) {
        const int col = wc + n * 16 + fr;
        const int c = kk * 4 + fg;
        bfr[n][kk] = *(const short8*)&Bb[col * 64 + ((c ^ (col & 7)) * 8)];
      }
#pragma unroll
    for (int kk = 0; kk < 2; ++kk)
#pragma unroll
      for (int m = 0; m < 4; ++m)
#pragma unroll
        for (int n = 0; n < 4; ++n)
          acc[m][n] = MFMA(af[m][kk], bfr[n][kk], acc[m][n]);
  }

  float bv[4];
#pragma unroll
  for (int n = 0; n < 4; ++n) bv[n] = bias[tn * 128 + wc + n * 16 + fr];
#pragma unroll
  for (int m = 0; m < 4; ++m)
#pragma unroll
    for (int n = 0; n < 4; ++n) {
      const long col = brow0 + wc + n * 16 + fr;
#pragma unroll
      for (int r = 0; r < 4; ++r) {
        const long row = arow0 + wr + m * 16 + fg * 4 + r;
        float v = acc[m][n][r] + bv[n];
        if (ACT == 1) v = fmaxf(v, 0.f);
        if (OUT8) ((unsigned char*)Cv)[row * (long)N + col] = f2fp8(v);
        else      ((short*)Cv)[row * (long)N + col] = f2bf(v);
      }
    }
}

// ---- GEMM fp8 x fp8 -> fp8 (relu): A[M][K] fp8, Bt[N][K] fp8, 128x128 tile, BK=64 ----
template<int N, int K, int ACT>
__global__ __launch_bounds__(256, 4)
void gemm_f8(const unsigned char* __restrict__ A, const unsigned char* __restrict__ Bt,
             const float* __restrict__ bias, unsigned char* __restrict__ C) {
  constexpr int NT = K / 64;
  constexpr int NTN = N / 128;
  __shared__ __align__(16) unsigned char As[2][128 * 64];
  __shared__ __align__(16) unsigned char Bs[2][128 * 64];
  const int tid = threadIdx.x;
  const int wave = tid >> 6;
  const int lane = tid & 63;
  const int Mtiles = gridDim.x / NTN;
  const int bid = blockIdx.x;
  const int xcd = bid & 7, seq = bid >> 3;
  const int tm = xcd * (Mtiles >> 3) + seq / NTN;
  const int tn = seq % NTN;
  const long arow0 = (long)tm * 128;
  const long brow0 = (long)tn * 128;

  auto stage = [&](int b, int kt) {
    const int k0 = kt * 64;
#pragma unroll
    for (int it = 0; it < 2; ++it) {
      const int ch = it * 256 + tid;       // 16B chunk 0..511
      const int row = ch >> 2;
      const int cs = (ch & 3) ^ (row & 3); // inverse-swizzled source chunk
      gl_lds16(A + (arow0 + row) * (long)K + k0 + cs * 16, &As[b][ch * 16]);
      gl_lds16(Bt + (brow0 + row) * (long)K + k0 + cs * 16, &Bs[b][ch * 16]);
    }
  };

  const int wr = (wave >> 1) * 64;
  const int wc = (wave & 1) * 64;
  const int fr = lane & 15;
  const int fg = lane >> 4;

  f32x4 acc[4][4] = {};

  stage(0, 0);
  for (int kt = 0; kt < NT; ++kt) {
    const int cur = kt & 1;
    __syncthreads();
    if (kt + 1 < NT) stage(cur ^ 1, kt + 1);
    const unsigned char* Ab = As[cur];
    const unsigned char* Bb = Bs[cur];
    long long af[4][2], bfr[4][2];
#pragma unroll
    for (int m = 0; m < 4; ++m)
#pragma unroll
      for (int kk = 0; kk < 2; ++kk) {
        const int row = wr + m * 16 + fr;
        const int c16 = (kk * 2 + (fg >> 1)) ^ (row & 3);
        af[m][kk] = *(const long long*)&Ab[row * 64 + c16 * 16 + (fg & 1) * 8];
      }
#pragma unroll
    for (int n = 0; n < 4; ++n)
#pragma unroll
      for (int kk = 0; kk < 2; ++kk) {
        const int col = wc + n * 16 + fr;
        const int c16 = (kk * 2 + (fg >> 1)) ^ (col & 3);
        bfr[n][kk] = *(const long long*)&Bb[col * 64 + c16 * 16 + (fg & 1) * 8];
      }
#pragma unroll
    for (int kk = 0; kk < 2; ++kk)
#pragma unroll
      for (int m = 0; m < 4; ++m)
#pragma unroll
        for (int n = 0; n < 4; ++n)
          acc[m][n] = MFMA8(af[m][kk], bfr[n][kk], acc[m][n]);
  }

  float bv[4];
#pragma unroll
  for (int n = 0; n < 4; ++n) bv[n] = bias[tn * 128 + wc + n * 16 + fr];
#pragma unroll
  for (int m = 0; m < 4; ++m)
#pragma unroll
    for (int n = 0; n < 4; ++n) {
      const long col = brow0 + wc + n * 16 + fr;
#pragma unroll
      for (int r = 0; r < 4; ++r) {
        const long row = arow0 + wr + m * 16 + fg * 4 + r;
        float v = acc[m][n][r] + bv[n];
        if (ACT == 1) v = fmaxf(v, 0.f);
        C[row * (long)N + col] = f2fp8(v);
      }
    }
}

// ============ K2 (64 rows/block): branch(h2@w3, fp8 MFMA) * trunk -> 13-dim out ============
__global__ __launch_bounds__(512)
void k2(const unsigned char* __restrict__ h2, const float* __restrict__ state,
        const float* __restrict__ tw1, const float* __restrict__ tb1,
        const unsigned char* __restrict__ w3f, const float* __restrict__ bb3,
        const short* __restrict__ w4T, const float* __restrict__ tb2,
        const short* __restrict__ pwT, const short* __restrict__ qw1T,
        const short* __restrict__ qw2T, const float* __restrict__ qb1,
        const float* __restrict__ pb, const float* __restrict__ qb2,
        const float* __restrict__ rwp, float* __restrict__ out) {
  __shared__ __align__(16) char lds[114688];
  short* tS  = (short*)lds;              // [64][256] swz8: 32768; later inter
  char*  stg = lds + 32768;              // branch dbuf 2x10240 / trunk dbuf 2x16384
  short* hqS = (short*)(lds + 65536);    // [64][128] swz8: 16384
  short* pwS = (short*)(lds + 81920);    // [16][256] swz8: 8192
  short* q2S = (short*)(lds + 90112);    // [16][128] swz8: 4096
  short* ppS = (short*)(lds + 94208);    // posPad [64][32] swz4: 4096
  short* q1S = (short*)(lds + 98304);    // qw1T [128][32] swz4: 8192
  float* prS = (float*)(lds + 106496);   // [64][16] f32
  float* pr2S= (float*)(lds + 110592);   // [64][16] f32

  const int tid = threadIdx.x, wave = tid >> 6, lane = tid & 63;
  const int fr = lane & 15, fg = lane >> 4;
  const long rb = (long)blockIdx.x * 64;

  // ---- phase 1: stage small weights, build t / posPad ----
  {
    int chk = wave * 64 + lane;
    { int row = chk >> 5, c = chk & 31;
      gl_lds16(pwT + (long)row * 256 + swz8(c, row) * 8, (char*)pwS + wave * 1024); }
    if (wave < 4) { int row = chk >> 4, c = chk & 15;
      gl_lds16(qw2T + (long)row * 128 + swz8(c, row) * 8, (char*)q2S + wave * 1024); }
    { int row = chk >> 2, c = chk & 3;
      gl_lds16(qw1T + (long)row * 32 + swz4(c, row) * 8, (char*)q1S + wave * 1024); }
  }
  for (int i = tid; i < 64 * 32; i += 512) {   // t = tanh(pos @ tw1 + tb1)
    int r = i >> 5, c8 = i & 31;
    float p0 = state[(rb + r) * 13 + 0], p1 = state[(rb + r) * 13 + 1], p2 = state[(rb + r) * 13 + 2];
    short8 v;
#pragma unroll
    for (int j = 0; j < 8; ++j) {
      int jj = c8 * 8 + j;
      v[j] = f2bf(tanhf(p0 * tw1[jj] + p1 * tw1[256 + jj] + p2 * tw1[512 + jj] + tb1[jj]));
    }
    *(short8*)&tS[(r * 32 + swz8(c8, r)) * 8] = v;
  }
  if (tid < 256) {                             // posPad [64][32] bf16
    int r = tid >> 2, c = tid & 3;
    float p0 = state[(rb + r) * 13 + 0], p1 = state[(rb + r) * 13 + 1], p2 = state[(rb + r) * 13 + 2];
    short8 v;
#pragma unroll
    for (int j = 0; j < 8; ++j) {
      int k = c * 8 + j;
      v[j] = (k == 0) ? f2bf(p0) : (k == 1) ? f2bf(p1) : (k == 2) ? f2bf(p2) : (short)0;
    }
    *(short8*)&ppS[(r * 4 + swz4(c, r)) * 8] = v;
  }

  // ---- branch gemm: fp8, K=512, wave tile 64x32 (1M x 8N) ----
  auto stageBr = [&](int buf, int ks) {
    char* d = stg + buf * 10240;
    int ch = wave * 64 + lane;
    if (wave < 2) { int row = ch >> 1, c = (ch & 1) ^ (row & 1);
      gl_lds16(h2 + (rb + row) * 512 + ks * 32 + c * 16, d + wave * 1024); }
    { int row = ch >> 1, c = (ch & 1) ^ (row & 1);
      gl_lds16(w3f + (long)row * 512 + ks * 32 + c * 16, d + 2048 + wave * 1024); }
  };
  f32x4 acc3[4][2] = {};
  stageBr(0, 0);
  __syncthreads();
#pragma unroll
  for (int ks = 0; ks < 16; ++ks) {
    if (ks) __syncthreads();
    if (ks < 15) stageBr((ks & 1) ^ 1, ks + 1);
    const char* Ab = stg + (ks & 1) * 10240;
    const char* Bb = Ab + 2048;
    long long a[4], b[2];
#pragma unroll
    for (int mf = 0; mf < 4; ++mf) { int row = mf * 16 + fr;
      a[mf] = *(const long long*)(Ab + row * 32 + (((fg >> 1) ^ (row & 1)) << 4) + ((fg & 1) << 3)); }
#pragma unroll
    for (int nf = 0; nf < 2; ++nf) { int col = wave * 32 + nf * 16 + fr;
      b[nf] = *(const long long*)(Bb + col * 32 + (((fg >> 1) ^ (col & 1)) << 4) + ((fg & 1) << 3)); }
#pragma unroll
    for (int mf = 0; mf < 4; ++mf)
#pragma unroll
      for (int nf = 0; nf < 2; ++nf)
        acc3[mf][nf] = MFMA8(a[mf], b[nf], acc3[mf][nf]);
  }
  __syncthreads();  // branch staging reads done -> stg reusable

  // ---- trunk gemm: bf16, K=256, A = tS resident, wave tile 64x32 ----
  auto stageTr = [&](int buf, int ks) {
    char* dst = stg + buf * 16384;
#pragma unroll
    for (int it = 0; it < 2; ++it) {
      int cw = it * 8 + wave;
      int chk = cw * 64 + lane;
      int row = chk >> 2, c = chk & 3;
      gl_lds16(w4T + (long)row * 256 + ks * 32 + swz4(c, row) * 8, dst + cw * 1024);
    }
  };
  f32x4 accT[4][2] = {};
  stageTr(0, 0);
#pragma unroll
  for (int ks = 0; ks < 8; ++ks) {
    __syncthreads();
    if (ks < 7) stageTr((ks & 1) ^ 1, ks + 1);
    const short* Bb = (const short*)(stg + (ks & 1) * 16384);
    short8 aF[4], bF[2];
#pragma unroll
    for (int mf = 0; mf < 4; ++mf) { int row = mf * 16 + fr;
      aF[mf] = *(const short8*)&tS[row * 256 + swz8(ks * 4 + fg, row) * 8]; }
#pragma unroll
    for (int nf = 0; nf < 2; ++nf) { int col = wave * 32 + nf * 16 + fr;
      bF[nf] = *(const short8*)&Bb[col * 32 + swz4(fg, col) * 8]; }
#pragma unroll
    for (int mf = 0; mf < 4; ++mf)
#pragma unroll
      for (int nf = 0; nf < 2; ++nf)
        accT[mf][nf] = MFMA(aF[mf], bF[nf], accT[mf][nf]);
  }
  __syncthreads();  // all tS reads done -> tS reusable as inter

  // ---- interaction -> tS; bias-net hq = relu(posPad @ qw1T + qb1) -> hqS ----
#pragma unroll
  for (int nf = 0; nf < 2; ++nf) {
    int col = wave * 32 + nf * 16 + fr;
    float b3 = bb3[col], t2 = tb2[col];
#pragma unroll
    for (int mf = 0; mf < 4; ++mf)
#pragma unroll
      for (int i = 0; i < 4; ++i) {
        int row = mf * 16 + fg * 4 + i;
        float br = acc3[mf][nf][i] + b3;
        float tr = tanhf(accT[mf][nf][i] + t2);
        tS[row * 256 + swz8(col >> 3, row) * 8 + (col & 7)] = f2bf(br * tr);
      }
  }
  {
    short8 aF[4];
#pragma unroll
    for (int mf = 0; mf < 4; ++mf) { int row = mf * 16 + fr;
      aF[mf] = *(const short8*)&ppS[row * 32 + swz4(fg, row) * 8]; }
    int col = wave * 16 + fr;
    short8 bF = *(const short8*)&q1S[col * 32 + swz4(fg, col) * 8];
    f32x4 aq[4] = {};
#pragma unroll
    for (int mf = 0; mf < 4; ++mf) aq[mf] = MFMA(aF[mf], bF, aq[mf]);
    float qb = qb1[col];
#pragma unroll
    for (int mf = 0; mf < 4; ++mf)
#pragma unroll
      for (int i = 0; i < 4; ++i) {
        int row = mf * 16 + fg * 4 + i;
        float v = fmaxf(aq[mf][i] + qb, 0.f);
        hqS[row * 128 + swz8(col >> 3, row) * 8 + (col & 7)] = f2bf(v);
      }
  }
  __syncthreads();  // inter + hq visible

  // ---- proj: waves 0-3: inter @ pwT (K=256); waves 4-7: hq @ qw2T (K=128) ----
  if (wave < 4) {
    int row = wave * 16 + fr;
    f32x4 accP = {0.f, 0.f, 0.f, 0.f};
#pragma unroll
    for (int ks = 0; ks < 8; ++ks) {
      short8 a = *(const short8*)&tS[row * 256 + swz8(ks * 4 + fg, row) * 8];
      short8 b = *(const short8*)&pwS[fr * 256 + swz8(ks * 4 + fg, fr) * 8];
      accP = MFMA(a, b, accP);
    }
#pragma unroll
    for (int i = 0; i < 4; ++i)
      prS[(wave * 16 + fg * 4 + i) * 16 + fr] = accP[i];
  } else {
    int row = (wave - 4) * 16 + fr;
    f32x4 accQ = {0.f, 0.f, 0.f, 0.f};
#pragma unroll
    for (int ks = 0; ks < 4; ++ks) {
      short8 a = *(const short8*)&hqS[row * 128 + swz8(ks * 4 + fg, row) * 8];
      short8 b = *(const short8*)&q2S[fr * 128 + swz8(ks * 4 + fg, fr) * 8];
      accQ = MFMA(a, b, accQ);
    }
#pragma unroll
    for (int i = 0; i < 4; ++i)
      pr2S[((wave - 4) * 16 + fg * 4 + i) * 16 + fr] = accQ[i];
  }
  __syncthreads();

  // ---- epilogue: residual + quat normalize ----
  if (tid < 64) {
    int r = tid;
    float rw = rwp[0];
    float ns[13];
#pragma unroll
    for (int c = 0; c < 13; ++c)
      ns[c] = state[(rb + r) * 13 + c] + rw * (prS[r * 16 + c] + pr2S[r * 16 + c] + pb[c] + qb2[c]);
    float qn = sqrtf(ns[3] * ns[3] + ns[4] * ns[4] + ns[5] * ns[5] + ns[6] * ns[6]) + 1e-8f;
#pragma unroll
    for (int c = 3; c < 7; ++c) ns[c] /= qn;
#pragma unroll
    for (int c = 0; c < 13; ++c) out[(rb + r) * 13 + c] = ns[c];
  }
}

extern "C" void kernel_launch(void* const* d_in, const int* in_sizes, int n_in,
                              void* d_out, int out_size, void* d_ws, size_t ws_size,
                              hipStream_t stream) {
  const float* state  = (const float*)d_in[0];
  const float* action = (const float*)d_in[1];
  const float* sensors= (const float*)d_in[2];
  const float* bw1 = (const float*)d_in[3];
  const float* bb1 = (const float*)d_in[4];
  const float* bw2 = (const float*)d_in[5];
  const float* bb2 = (const float*)d_in[6];
  const float* bw3 = (const float*)d_in[7];
  const float* bb3 = (const float*)d_in[8];
  const float* tw1 = (const float*)d_in[9];
  const float* tb1 = (const float*)d_in[10];
  const float* tw2 = (const float*)d_in[11];
  const float* tb2 = (const float*)d_in[12];
  const float* qw1 = (const float*)d_in[13];
  const float* qb1 = (const float*)d_in[14];
  const float* qw2 = (const float*)d_in[15];
  const float* qb2 = (const float*)d_in[16];
  const float* pw  = (const float*)d_in[17];
  const float* pb  = (const float*)d_in[18];
  const float* rw  = (const float*)d_in[19];
  float* out = (float*)d_out;

  char* p = (char*)d_ws;
  short* w1T = (short*)p;          p += (size_t)1024 * 576 * 2;
  unsigned char* w2f = (unsigned char*)p; p += (size_t)512 * 1024;
  unsigned char* w3f = (unsigned char*)p; p += (size_t)256 * 512;
  short* w4T = (short*)p;          p += (size_t)256 * 256 * 2;
  short* pwT = (short*)p;          p += (size_t)16 * 256 * 2;
  short* qw1T= (short*)p;          p += (size_t)128 * 32 * 2;
  short* qw2T= (short*)p;          p += (size_t)16 * 128 * 2;
  const size_t fixed = (size_t)(p - (char*)d_ws);
  const size_t avail = (ws_size > fixed) ? ws_size - fixed : 0;
  // per-row: enc 1152B (bf16, h2 fp8 512B overlays after gemm1) + h1f 1024B fp8
  long Mc = (long)(avail / 2176) & ~1023L;   // multiple of 1024 rows (XCD remap needs Mtiles%8==0)
  if (Mc > B_TOTAL) Mc = B_TOTAL;
  if (Mc < 1024) return;
  short* encb = (short*)p;                         // Mc*576 bf16; h2 fp8 overlays
  unsigned char* h2b = (unsigned char*)p;
  unsigned char* h1f = (unsigned char*)(p + (size_t)Mc * 1152);  // Mc*1024 fp8

  prep<<<dim3(1281), dim3(256), 0, stream>>>(bw1, bw2, bw3, tw2, pw, qw1, qw2,
                                             w1T, w2f, w3f, w4T, pwT, qw1T, qw2T);

  for (long r0 = 0; r0 < B_TOTAL; r0 += Mc) {
    long Mr = B_TOTAL - r0; if (Mr > Mc) Mr = Mc;
    enc_k<<<dim3(Mr / 64), dim3(256), 0, stream>>>(state + r0 * 13, action + r0 * 4,
                                                   sensors, encb);
    gemm_bt<1024, 576, 576, 1, 1><<<dim3((Mr / 128) * 8), dim3(256), 0, stream>>>(
        encb, w1T, bb1, h1f);
    gemm_f8<512, 1024, 1><<<dim3((Mr / 128) * 4), dim3(256), 0, stream>>>(
        h1f, w2f, bb2, h2b);
    k2<<<dim3(Mr / 64), dim3(512), 0, stream>>>(h2b, state + r0 * 13, tw1, tb1,
                                                w3f, bb3, w4T, tb2, pwT, qw1T, qw2T,
                                                qb1, pb, qb2, rw, out + r0 * 13);
  }
}

// Round 6
// 444.309 us; speedup vs baseline: 1.6655x; 1.3242x over previous
//
#include <hip/hip_runtime.h>
#include <hip/hip_bf16.h>
#include <hip/hip_fp8.h>

#define B_TOTAL 131072

typedef __attribute__((ext_vector_type(8))) short short8;   // 8 bf16 MFMA A/B frag
typedef __attribute__((ext_vector_type(4))) float f32x4;    // MFMA C/D frag
typedef __attribute__((ext_vector_type(16))) unsigned char uchar16;
typedef unsigned int uint;

#define MFMA(a,b,c) __builtin_amdgcn_mfma_f32_16x16x32_bf16(a,b,c,0,0,0)
#define MFMA8(a,b,c) __builtin_amdgcn_mfma_f32_16x16x32_fp8_fp8(a,b,c,0,0,0)

__device__ __forceinline__ short f2bf(float f) {
  union { float f; uint u; } x; x.f = f;
  uint r = x.u + 0x7fffu + ((x.u >> 16) & 1u);  // RTNE
  return (short)(r >> 16);
}
__device__ __forceinline__ unsigned char f2fp8(float v) {
  union { __hip_fp8_e4m3 q; unsigned char b; } u;
  u.q = __hip_fp8_e4m3(v);
  return u.b;
}
// fast tanh: 1 - 2/(exp(2x)+1) via v_exp_f32 + v_rcp_f32 (~5 instrs vs ~70 libm)
__device__ __forceinline__ float ftanh(float x) {
  float e = __builtin_amdgcn_exp2f(x * 2.8853900817779268f);   // exp(2x)
  return 1.f - 2.f * __builtin_amdgcn_rcpf(e + 1.f);
}

__device__ __forceinline__ void gl_lds16(const void* g, void* l) {
  __builtin_amdgcn_global_load_lds((const __attribute__((address_space(1))) uint*)g,
                                   (__attribute__((address_space(3))) uint*)l, 16, 0, 0);
}
__device__ __forceinline__ int swz8(int c, int r) { return (c & ~7) | ((c ^ r) & 7); }

// ============ merged weight prep: LDS-tiled transpose, coalesced both sides ============
// w1f[1024][576] fp8 | w2f[512][1024] fp8 | w3f[256][512] fp8 | w4T[256][256] bf16 | smalls
__global__ __launch_bounds__(256)
void prep(const float* __restrict__ bw1, const float* __restrict__ bw2,
          const float* __restrict__ bw3, const float* __restrict__ tw2,
          const float* __restrict__ pw, const float* __restrict__ qw2,
          unsigned char* __restrict__ w1f, unsigned char* __restrict__ w2f,
          unsigned char* __restrict__ w3f, short* __restrict__ w4T,
          short* __restrict__ pwT, short* __restrict__ qw2T) {
  __shared__ float tile[32][33];
  int b = blockIdx.x;
  if (b == 1280) {  // small weights, scattered (tiny)
    for (int t = threadIdx.x; t < 6144; t += 256) {
      if (t < 4096) { int c = t >> 8, k = t & 255;
        pwT[t] = (c < 13) ? f2bf(pw[k * 13 + c]) : (short)0; }
      else { int i = t - 4096; int c = i >> 7, j = i & 127;
        qw2T[i] = (c < 13) ? f2bf(qw2[j * 13 + c]) : (short)0; }
    }
    return;
  }
  const float* src; void* dst; int K, N, Kpad, ntk, dt8;
  if (b < 576)       { src = bw1; dst = w1f; K = 544;  N = 1024; Kpad = 576;  ntk = 18; dt8 = 1; }
  else if (b < 1088) { b -= 576;  src = bw2; dst = w2f; K = 1024; N = 512;  Kpad = 1024; ntk = 32; dt8 = 1; }
  else if (b < 1216) { b -= 1088; src = bw3; dst = w3f; K = 512;  N = 256;  Kpad = 512;  ntk = 16; dt8 = 1; }
  else               { b -= 1216; src = tw2; dst = w4T; K = 256;  N = 256;  Kpad = 256;  ntk = 8;  dt8 = 0; }
  const int tn = b / ntk, tk = b % ntk;
  const int k0 = tk * 32, n0 = tn * 32;
  const int tx = threadIdx.x & 31, ty = threadIdx.x >> 5;
#pragma unroll
  for (int rr = 0; rr < 32; rr += 8) {
    int k = k0 + ty + rr;
    tile[ty + rr][tx] = (k < K) ? src[(long)k * N + n0 + tx] : 0.f;
  }
  __syncthreads();
#pragma unroll
  for (int rr = 0; rr < 32; rr += 8) {
    int nl = ty + rr;
    float v = tile[tx][nl];
    if (dt8) ((unsigned char*)dst)[(long)(n0 + nl) * Kpad + k0 + tx] = f2fp8(v);
    else     ((short*)dst)[(long)(n0 + nl) * Kpad + k0 + tx] = f2bf(v);
  }
}

// ---- enc kernel: builds enc[M][576] fp8 (zero-padded cols 544..575) ----
__global__ __launch_bounds__(256)
void enc_k(const float* __restrict__ state, const float* __restrict__ action,
           const float* __restrict__ sensors, unsigned char* __restrict__ enc) {
  __shared__ float sval[64][17];
  __shared__ float wexp[64][32];
  __shared__ float sens[96];
  const int tid = threadIdx.x;
  const int rb = blockIdx.x * 64;
  if (tid < 96) sens[tid] = sensors[tid];
  for (int i = tid; i < 64 * 17; i += 256) {
    const int r = i / 17, c = i % 17;
    const long grow = rb + r;
    sval[r][c] = (c < 13) ? state[grow * 13 + c] : action[grow * 4 + (c - 13)];
  }
  __syncthreads();
  for (int i = tid; i < 64 * 32; i += 256) {
    const int r = i >> 5, s = i & 31;
    const float dx = sens[s*3+0] - sval[r][0];
    const float dy = sens[s*3+1] - sval[r][1];
    const float dz = sens[s*3+2] - sval[r][2];
    wexp[r][s] = __expf(-2.0f * sqrtf(dx*dx + dy*dy + dz*dz));
  }
  __syncthreads();
  for (int i = tid; i < 64 * 36; i += 256) {
    const int r = i / 36, c16 = i % 36;
    uchar16 v;
#pragma unroll
    for (int j = 0; j < 16; ++j) {
      const int k = c16 * 16 + j;
      unsigned char o = 0;
      if (k < 544) { const int s = k / 17, c = k % 17; o = f2fp8(sval[r][c] * wexp[r][s]); }
      v[j] = o;
    }
    *(uchar16*)&enc[((long)(rb + r)) * 576 + c16 * 16] = v;
  }
}

// ---- GEMM fp8 x fp8 -> fp8 (relu): A[M][K] fp8, Bt[N][K] fp8, 128x128 tile, BK=64 ----
template<int N, int K, int ACT>
__global__ __launch_bounds__(256, 4)
void gemm_f8(const unsigned char* __restrict__ A, const unsigned char* __restrict__ Bt,
             const float* __restrict__ bias, unsigned char* __restrict__ C) {
  constexpr int NT = K / 64;
  constexpr int NTN = N / 128;
  __shared__ __align__(16) unsigned char As[2][128 * 64];
  __shared__ __align__(16) unsigned char Bs[2][128 * 64];
  const int tid = threadIdx.x;
  const int wave = tid >> 6;
  const int lane = tid & 63;
  // XCD-aware remap: all NTN blocks of one tm land on one XCD, adjacent in time.
  const int Mtiles = gridDim.x / NTN;
  const int bid = blockIdx.x;
  const int xcd = bid & 7, seq = bid >> 3;
  const int tm = xcd * (Mtiles >> 3) + seq / NTN;
  const int tn = seq % NTN;
  const long arow0 = (long)tm * 128;
  const long brow0 = (long)tn * 128;

  auto stage = [&](int b, int kt) {
    const int k0 = kt * 64;
#pragma unroll
    for (int it = 0; it < 2; ++it) {
      const int ch = it * 256 + tid;       // 16B chunk 0..511
      const int row = ch >> 2;
      const int cs = (ch & 3) ^ (row & 3); // inverse-swizzled source chunk
      gl_lds16(A + (arow0 + row) * (long)K + k0 + cs * 16, &As[b][ch * 16]);
      gl_lds16(Bt + (brow0 + row) * (long)K + k0 + cs * 16, &Bs[b][ch * 16]);
    }
  };

  const int wr = (wave >> 1) * 64;
  const int wc = (wave & 1) * 64;
  const int fr = lane & 15;
  const int fg = lane >> 4;

  f32x4 acc[4][4] = {};

  stage(0, 0);
  for (int kt = 0; kt < NT; ++kt) {
    const int cur = kt & 1;
    __syncthreads();
    if (kt + 1 < NT) stage(cur ^ 1, kt + 1);
    const unsigned char* Ab = As[cur];
    const unsigned char* Bb = Bs[cur];
    long long af[4][2], bfr[4][2];
#pragma unroll
    for (int m = 0; m < 4; ++m)
#pragma unroll
      for (int kk = 0; kk < 2; ++kk) {
        const int row = wr + m * 16 + fr;
        const int c16 = (kk * 2 + (fg >> 1)) ^ (row & 3);
        af[m][kk] = *(const long long*)&Ab[row * 64 + c16 * 16 + (fg & 1) * 8];
      }
#pragma unroll
    for (int n = 0; n < 4; ++n)
#pragma unroll
      for (int kk = 0; kk < 2; ++kk) {
        const int col = wc + n * 16 + fr;
        const int c16 = (kk * 2 + (fg >> 1)) ^ (col & 3);
        bfr[n][kk] = *(const long long*)&Bb[col * 64 + c16 * 16 + (fg & 1) * 8];
      }
#pragma unroll
    for (int kk = 0; kk < 2; ++kk)
#pragma unroll
      for (int m = 0; m < 4; ++m)
#pragma unroll
        for (int n = 0; n < 4; ++n)
          acc[m][n] = MFMA8(af[m][kk], bfr[n][kk], acc[m][n]);
  }

  float bv[4];
#pragma unroll
  for (int n = 0; n < 4; ++n) bv[n] = bias[tn * 128 + wc + n * 16 + fr];
#pragma unroll
  for (int m = 0; m < 4; ++m)
#pragma unroll
    for (int n = 0; n < 4; ++n) {
      const long col = brow0 + wc + n * 16 + fr;
#pragma unroll
      for (int r = 0; r < 4; ++r) {
        const long row = arow0 + wr + m * 16 + fg * 4 + r;
        float v = acc[m][n][r] + bv[n];
        if (ACT == 1) v = fmaxf(v, 0.f);
        C[row * (long)N + col] = f2fp8(v);
      }
    }
}

// ============ K2 (64 rows/block): branch * trunk -> 13-dim out. 4 barriers total. ============
// A panels staged once in LDS; B operands (w3f/w4T, L2-resident) read direct to registers.
__global__ __launch_bounds__(512, 4)
void k2(const unsigned char* __restrict__ h2, const float* __restrict__ state,
        const float* __restrict__ tw1, const float* __restrict__ tb1,
        const unsigned char* __restrict__ w3f, const float* __restrict__ bb3,
        const short* __restrict__ w4T, const float* __restrict__ tb2,
        const short* __restrict__ pwT, const float* __restrict__ qw1,
        const short* __restrict__ qw2T, const float* __restrict__ qb1,
        const float* __restrict__ pb, const float* __restrict__ qb2,
        const float* __restrict__ rwp, float* __restrict__ out) {
  __shared__ __align__(16) char lds[77824];
  char*  h2S = lds;                    // [64][512] fp8 (16B-granule XOR swz): 32768
  short* tS  = (short*)(lds + 32768);  // [64][256] bf16 swz8: 32768; later inter
  short* pwS = (short*)(lds + 65536);  // [16][256] swz8: 8192
  short* q2S = (short*)(lds + 73728);  // [16][128] swz8: 4096
  short* hqS = (short*)lds;            // [64][128] swz8 (16384) — overlays h2S after branch
  float* prS = (float*)(lds + 16384);  // [64][16]
  float* pr2S= (float*)(lds + 20480);  // [64][16]

  const int tid = threadIdx.x, wave = tid >> 6, lane = tid & 63;
  const int fr = lane & 15, fg = lane >> 4;
  const long rb = (long)blockIdx.x * 64;

  // ---- stage h2 panel (pre-swizzled source), pwT, qw2T; then t-build overlaps latency ----
#pragma unroll
  for (int it = 0; it < 4; ++it) {
    int ch = it * 512 + tid;
    int row = ch >> 5, c = ch & 31;
    gl_lds16(h2 + (rb + row) * 512 + ((c ^ (row & 7)) << 4), h2S + ch * 16);
  }
  { int row = tid >> 5, c = tid & 31;
    gl_lds16(pwT + (long)row * 256 + swz8(c, row) * 8, (char*)pwS + tid * 16); }
  if (tid < 256) { int row = tid >> 4, c = tid & 15;
    gl_lds16(qw2T + (long)row * 128 + swz8(c, row) * 8, (char*)q2S + tid * 16); }

  for (int i = tid; i < 64 * 32; i += 512) {   // t = ftanh(pos @ tw1 + tb1) -> tS
    int r = i >> 5, c8 = i & 31;
    float p0 = state[(rb + r) * 13 + 0], p1 = state[(rb + r) * 13 + 1], p2 = state[(rb + r) * 13 + 2];
    short8 v;
#pragma unroll
    for (int j = 0; j < 8; ++j) {
      int jj = c8 * 8 + j;
      v[j] = f2bf(ftanh(p0 * tw1[jj] + p1 * tw1[256 + jj] + p2 * tw1[512 + jj] + tb1[jj]));
    }
    *(short8*)&tS[(r * 32 + swz8(c8, r)) * 8] = v;
  }
  __syncthreads();   // barrier 1: h2S/pwS/q2S staged (vmcnt drained), tS built

  const int col0 = wave * 32 + fr, col1 = col0 + 16;

  // ---- branch gemm: fp8, K=512, no barriers. A=h2S(LDS), B=w3f(global L2) ----
  f32x4 acc3[4][2] = {};
#pragma unroll
  for (int ks = 0; ks < 16; ++ks) {
    long long b0 = *(const long long*)&w3f[(long)col0 * 512 + ks * 32 + fg * 8];
    long long b1 = *(const long long*)&w3f[(long)col1 * 512 + ks * 32 + fg * 8];
    long long a[4];
#pragma unroll
    for (int mf = 0; mf < 4; ++mf) {
      int row = mf * 16 + fr;
      int c16 = (ks * 2 + (fg >> 1)) ^ (row & 7);
      a[mf] = *(const long long*)&h2S[row * 512 + c16 * 16 + ((fg & 1) << 3)];
    }
#pragma unroll
    for (int mf = 0; mf < 4; ++mf) {
      acc3[mf][0] = MFMA8(a[mf], b0, acc3[mf][0]);
      acc3[mf][1] = MFMA8(a[mf], b1, acc3[mf][1]);
    }
  }

  // ---- trunk gemm: bf16, K=256, no barriers. A=tS(LDS), B=w4T(global L2) ----
  f32x4 accT[4][2] = {};
#pragma unroll
  for (int ks = 0; ks < 8; ++ks) {
    short8 b0 = *(const short8*)&w4T[(long)col0 * 256 + ks * 32 + fg * 8];
    short8 b1 = *(const short8*)&w4T[(long)col1 * 256 + ks * 32 + fg * 8];
#pragma unroll
    for (int mf = 0; mf < 4; ++mf) {
      int row = mf * 16 + fr;
      short8 aF = *(const short8*)&tS[row * 256 + swz8(ks * 4 + fg, row) * 8];
      accT[mf][0] = MFMA(aF, b0, accT[mf][0]);
      accT[mf][1] = MFMA(aF, b1, accT[mf][1]);
    }
  }
  __syncthreads();   // barrier 2: all h2S/tS reads done -> regions reusable

  // ---- interaction -> tS (reuse); bias-net hq via VALU -> hqS (overlays h2S) ----
#pragma unroll
  for (int nf = 0; nf < 2; ++nf) {
    int col = wave * 32 + nf * 16 + fr;
    float b3 = bb3[col], t2 = tb2[col];
#pragma unroll
    for (int mf = 0; mf < 4; ++mf)
#pragma unroll
      for (int i = 0; i < 4; ++i) {
        int row = mf * 16 + fg * 4 + i;
        float br = acc3[mf][nf][i] + b3;
        float tr = ftanh(accT[mf][nf][i] + t2);
        tS[row * 256 + swz8(col >> 3, row) * 8 + (col & 7)] = f2bf(br * tr);
      }
  }
  {
    int r = tid >> 3, j0 = (tid & 7) * 16;
    float p0 = state[(rb + r) * 13 + 0], p1 = state[(rb + r) * 13 + 1], p2 = state[(rb + r) * 13 + 2];
#pragma unroll
    for (int cc = 0; cc < 2; ++cc) {
      short8 v;
#pragma unroll
      for (int j = 0; j < 8; ++j) {
        int jj = j0 + cc * 8 + j;
        float hv = fmaxf(p0 * qw1[jj] + p1 * qw1[128 + jj] + p2 * qw1[256 + jj] + qb1[jj], 0.f);
        v[j] = f2bf(hv);
      }
      *(short8*)&hqS[(r * 16 + swz8(j0 / 8 + cc, r)) * 8] = v;
    }
  }
  __syncthreads();   // barrier 3: inter + hq visible

  // ---- proj: waves 0-3: inter @ pwT (K=256); waves 4-7: hq @ qw2T (K=128) ----
  if (wave < 4) {
    int row = wave * 16 + fr;
    f32x4 accP = {0.f, 0.f, 0.f, 0.f};
#pragma unroll
    for (int ks = 0; ks < 8; ++ks) {
      short8 a = *(const short8*)&tS[row * 256 + swz8(ks * 4 + fg, row) * 8];
      short8 b = *(const short8*)&pwS[fr * 256 + swz8(ks * 4 + fg, fr) * 8];
      accP = MFMA(a, b, accP);
    }
#pragma unroll
    for (int i = 0; i < 4; ++i)
      prS[(wave * 16 + fg * 4 + i) * 16 + fr] = accP[i];
  } else {
    int row = (wave - 4) * 16 + fr;
    f32x4 accQ = {0.f, 0.f, 0.f, 0.f};
#pragma unroll
    for (int ks = 0; ks < 4; ++ks) {
      short8 a = *(const short8*)&hqS[row * 128 + swz8(ks * 4 + fg, row) * 8];
      short8 b = *(const short8*)&q2S[fr * 128 + swz8(ks * 4 + fg, fr) * 8];
      accQ = MFMA(a, b, accQ);
    }
#pragma unroll
    for (int i = 0; i < 4; ++i)
      pr2S[((wave - 4) * 16 + fg * 4 + i) * 16 + fr] = accQ[i];
  }
  __syncthreads();   // barrier 4

  // ---- epilogue: residual + quat normalize ----
  if (tid < 64) {
    int r = tid;
    float rw = rwp[0];
    float ns[13];
#pragma unroll
    for (int c = 0; c < 13; ++c)
      ns[c] = state[(rb + r) * 13 + c] + rw * (prS[r * 16 + c] + pr2S[r * 16 + c] + pb[c] + qb2[c]);
    float qn = sqrtf(ns[3] * ns[3] + ns[4] * ns[4] + ns[5] * ns[5] + ns[6] * ns[6]) + 1e-8f;
#pragma unroll
    for (int c = 3; c < 7; ++c) ns[c] /= qn;
#pragma unroll
    for (int c = 0; c < 13; ++c) out[(rb + r) * 13 + c] = ns[c];
  }
}

extern "C" void kernel_launch(void* const* d_in, const int* in_sizes, int n_in,
                              void* d_out, int out_size, void* d_ws, size_t ws_size,
                              hipStream_t stream) {
  const float* state  = (const float*)d_in[0];
  const float* action = (const float*)d_in[1];
  const float* sensors= (const float*)d_in[2];
  const float* bw1 = (const float*)d_in[3];
  const float* bb1 = (const float*)d_in[4];
  const float* bw2 = (const float*)d_in[5];
  const float* bb2 = (const float*)d_in[6];
  const float* bw3 = (const float*)d_in[7];
  const float* bb3 = (const float*)d_in[8];
  const float* tw1 = (const float*)d_in[9];
  const float* tb1 = (const float*)d_in[10];
  const float* tw2 = (const float*)d_in[11];
  const float* tb2 = (const float*)d_in[12];
  const float* qw1 = (const float*)d_in[13];
  const float* qb1 = (const float*)d_in[14];
  const float* qw2 = (const float*)d_in[15];
  const float* qb2 = (const float*)d_in[16];
  const float* pw  = (const float*)d_in[17];
  const float* pb  = (const float*)d_in[18];
  const float* rw  = (const float*)d_in[19];
  float* out = (float*)d_out;

  char* p = (char*)d_ws;
  unsigned char* w1f = (unsigned char*)p; p += (size_t)1024 * 576;
  unsigned char* w2f = (unsigned char*)p; p += (size_t)512 * 1024;
  unsigned char* w3f = (unsigned char*)p; p += (size_t)256 * 512;
  short* w4T = (short*)p;          p += (size_t)256 * 256 * 2;
  short* pwT = (short*)p;          p += (size_t)16 * 256 * 2;
  short* qw2T= (short*)p;          p += (size_t)16 * 128 * 2;
  const size_t fixed = (size_t)(p - (char*)d_ws);
  const size_t avail = (ws_size > fixed) ? ws_size - fixed : 0;
  // per-row: enc 576B fp8 (h2 fp8 512B overlays after gemm1) + h1f 1024B fp8
  long Mc = (long)(avail / 1600) & ~1023L;   // mult of 1024 (XCD remap: Mtiles%8==0)
  if (Mc > B_TOTAL) Mc = B_TOTAL;
  if (Mc < 1024) return;
  unsigned char* encb = (unsigned char*)p;               // Mc*576; h2 overlays
  unsigned char* h2b  = (unsigned char*)p;
  unsigned char* h1f  = (unsigned char*)(p + (size_t)Mc * 576);  // Mc*1024

  prep<<<dim3(1281), dim3(256), 0, stream>>>(bw1, bw2, bw3, tw2, pw, qw2,
                                             w1f, w2f, w3f, w4T, pwT, qw2T);

  for (long r0 = 0; r0 < B_TOTAL; r0 += Mc) {
    long Mr = B_TOTAL - r0; if (Mr > Mc) Mr = Mc;
    enc_k<<<dim3(Mr / 64), dim3(256), 0, stream>>>(state + r0 * 13, action + r0 * 4,
                                                   sensors, encb);
    gemm_f8<1024, 576, 1><<<dim3((Mr / 128) * 8), dim3(256), 0, stream>>>(
        encb, w1f, bb1, h1f);
    gemm_f8<512, 1024, 1><<<dim3((Mr / 128) * 4), dim3(256), 0, stream>>>(
        h1f, w2f, bb2, h2b);
    k2<<<dim3(Mr / 64), dim3(512), 0, stream>>>(h2b, state + r0 * 13, tw1, tb1,
                                                w3f, bb3, w4T, tb2, pwT, qw1, qw2T,
                                                qb1, pb, qb2, rw, out + r0 * 13);
  }
}

// Round 7
// 382.894 us; speedup vs baseline: 1.9327x; 1.1604x over previous
//
#include <hip/hip_runtime.h>
#include <hip/hip_bf16.h>
#include <hip/hip_fp8.h>

#define B_TOTAL 131072

typedef __attribute__((ext_vector_type(8))) short short8;   // 8 bf16 MFMA A/B frag
typedef __attribute__((ext_vector_type(4))) float f32x4;    // MFMA C/D frag
typedef __attribute__((ext_vector_type(16))) unsigned char uchar16;
typedef unsigned int uint;

#define MFMA(a,b,c) __builtin_amdgcn_mfma_f32_16x16x32_bf16(a,b,c,0,0,0)
#define MFMA8(a,b,c) __builtin_amdgcn_mfma_f32_16x16x32_fp8_fp8(a,b,c,0,0,0)

__device__ __forceinline__ short f2bf(float f) {
  union { float f; uint u; } x; x.f = f;
  uint r = x.u + 0x7fffu + ((x.u >> 16) & 1u);  // RTNE
  return (short)(r >> 16);
}
__device__ __forceinline__ unsigned char f2fp8(float v) {
  union { __hip_fp8_e4m3 q; unsigned char b; } u;
  u.q = __hip_fp8_e4m3(v);
  return u.b;
}
// fast tanh: 1 - 2/(exp(2x)+1) via v_exp_f32 + v_rcp_f32 (~5 instrs vs ~70 libm)
__device__ __forceinline__ float ftanh(float x) {
  float e = __builtin_amdgcn_exp2f(x * 2.8853900817779268f);   // exp(2x)
  return 1.f - 2.f * __builtin_amdgcn_rcpf(e + 1.f);
}

__device__ __forceinline__ void gl_lds16(const void* g, void* l) {
  __builtin_amdgcn_global_load_lds((const __attribute__((address_space(1))) uint*)g,
                                   (__attribute__((address_space(3))) uint*)l, 16, 0, 0);
}
__device__ __forceinline__ int swz8(int c, int r) { return (c & ~7) | ((c ^ r) & 7); }

// ============ merged weight prep: LDS-tiled transpose, coalesced both sides ============
__global__ __launch_bounds__(256)
void prep(const float* __restrict__ bw1, const float* __restrict__ bw2,
          const float* __restrict__ bw3, const float* __restrict__ tw2,
          const float* __restrict__ pw, const float* __restrict__ qw2,
          unsigned char* __restrict__ w1f, unsigned char* __restrict__ w2f,
          unsigned char* __restrict__ w3f, short* __restrict__ w4T,
          short* __restrict__ pwT, short* __restrict__ qw2T) {
  __shared__ float tile[32][33];
  int b = blockIdx.x;
  if (b == 1280) {  // small weights, scattered (tiny)
    for (int t = threadIdx.x; t < 6144; t += 256) {
      if (t < 4096) { int c = t >> 8, k = t & 255;
        pwT[t] = (c < 13) ? f2bf(pw[k * 13 + c]) : (short)0; }
      else { int i = t - 4096; int c = i >> 7, j = i & 127;
        qw2T[i] = (c < 13) ? f2bf(qw2[j * 13 + c]) : (short)0; }
    }
    return;
  }
  const float* src; void* dst; int K, N, Kpad, ntk, dt8;
  if (b < 576)       { src = bw1; dst = w1f; K = 544;  N = 1024; Kpad = 576;  ntk = 18; dt8 = 1; }
  else if (b < 1088) { b -= 576;  src = bw2; dst = w2f; K = 1024; N = 512;  Kpad = 1024; ntk = 32; dt8 = 1; }
  else if (b < 1216) { b -= 1088; src = bw3; dst = w3f; K = 512;  N = 256;  Kpad = 512;  ntk = 16; dt8 = 1; }
  else               { b -= 1216; src = tw2; dst = w4T; K = 256;  N = 256;  Kpad = 256;  ntk = 8;  dt8 = 0; }
  const int tn = b / ntk, tk = b % ntk;
  const int k0 = tk * 32, n0 = tn * 32;
  const int tx = threadIdx.x & 31, ty = threadIdx.x >> 5;
#pragma unroll
  for (int rr = 0; rr < 32; rr += 8) {
    int k = k0 + ty + rr;
    tile[ty + rr][tx] = (k < K) ? src[(long)k * N + n0 + tx] : 0.f;
  }
  __syncthreads();
#pragma unroll
  for (int rr = 0; rr < 32; rr += 8) {
    int nl = ty + rr;
    float v = tile[tx][nl];
    if (dt8) ((unsigned char*)dst)[(long)(n0 + nl) * Kpad + k0 + tx] = f2fp8(v);
    else     ((short*)dst)[(long)(n0 + nl) * Kpad + k0 + tx] = f2bf(v);
  }
}

// ---- enc kernel: builds enc[M][576] fp8 (zero-padded cols 544..575) ----
__global__ __launch_bounds__(256)
void enc_k(const float* __restrict__ state, const float* __restrict__ action,
           const float* __restrict__ sensors, unsigned char* __restrict__ enc) {
  __shared__ float sval[64][17];
  __shared__ float wexp[64][32];
  __shared__ float sens[96];
  const int tid = threadIdx.x;
  const int rb = blockIdx.x * 64;
  if (tid < 96) sens[tid] = sensors[tid];
  for (int i = tid; i < 64 * 17; i += 256) {
    const int r = i / 17, c = i % 17;
    const long grow = rb + r;
    sval[r][c] = (c < 13) ? state[grow * 13 + c] : action[grow * 4 + (c - 13)];
  }
  __syncthreads();
  for (int i = tid; i < 64 * 32; i += 256) {
    const int r = i >> 5, s = i & 31;
    const float dx = sens[s*3+0] - sval[r][0];
    const float dy = sens[s*3+1] - sval[r][1];
    const float dz = sens[s*3+2] - sval[r][2];
    wexp[r][s] = __expf(-2.0f * sqrtf(dx*dx + dy*dy + dz*dz));
  }
  __syncthreads();
  for (int i = tid; i < 64 * 36; i += 256) {
    const int r = i / 36, c16 = i % 36;
    uchar16 v;
#pragma unroll
    for (int j = 0; j < 16; ++j) {
      const int k = c16 * 16 + j;
      unsigned char o = 0;
      if (k < 544) { const int s = k / 17, c = k % 17; o = f2fp8(sval[r][c] * wexp[r][s]); }
      v[j] = o;
    }
    *(uchar16*)&enc[((long)(rb + r)) * 576 + c16 * 16] = v;
  }
}

// ---- GEMM fp8 x fp8 -> fp8 (relu): A[M][K] fp8, Bt[N][K] fp8, 128x128 tile, BK=64 ----
// Swizzle uses (row>>1)&3: 64B rows cover 4 chunk slots in the 128B bank space, so
// spreading consecutive SAME-PARITY rows across slots gives the minimum 2-way (free)
// instead of 4-way from (row&3).
template<int N, int K, int ACT>
__global__ __launch_bounds__(256, 4)
void gemm_f8(const unsigned char* __restrict__ A, const unsigned char* __restrict__ Bt,
             const float* __restrict__ bias, unsigned char* __restrict__ C) {
  constexpr int NT = K / 64;
  constexpr int NTN = N / 128;
  __shared__ __align__(16) unsigned char As[2][128 * 64];
  __shared__ __align__(16) unsigned char Bs[2][128 * 64];
  const int tid = threadIdx.x;
  const int wave = tid >> 6;
  const int lane = tid & 63;
  // XCD-aware remap: all NTN blocks of one tm land on one XCD, adjacent in time.
  const int Mtiles = gridDim.x / NTN;
  const int bid = blockIdx.x;
  const int xcd = bid & 7, seq = bid >> 3;
  const int tm = xcd * (Mtiles >> 3) + seq / NTN;
  const int tn = seq % NTN;
  const long arow0 = (long)tm * 128;
  const long brow0 = (long)tn * 128;

  auto stage = [&](int b, int kt) {
    const int k0 = kt * 64;
#pragma unroll
    for (int it = 0; it < 2; ++it) {
      const int ch = it * 256 + tid;       // 16B chunk 0..511
      const int row = ch >> 2;
      const int cs = (ch & 3) ^ ((row >> 1) & 3); // inverse-swizzled source chunk
      gl_lds16(A + (arow0 + row) * (long)K + k0 + cs * 16, &As[b][ch * 16]);
      gl_lds16(Bt + (brow0 + row) * (long)K + k0 + cs * 16, &Bs[b][ch * 16]);
    }
  };

  const int wr = (wave >> 1) * 64;
  const int wc = (wave & 1) * 64;
  const int fr = lane & 15;
  const int fg = lane >> 4;

  f32x4 acc[4][4] = {};

  stage(0, 0);
  for (int kt = 0; kt < NT; ++kt) {
    const int cur = kt & 1;
    __syncthreads();
    if (kt + 1 < NT) stage(cur ^ 1, kt + 1);
    const unsigned char* Ab = As[cur];
    const unsigned char* Bb = Bs[cur];
    long long af[4][2], bfr[4][2];
#pragma unroll
    for (int m = 0; m < 4; ++m)
#pragma unroll
      for (int kk = 0; kk < 2; ++kk) {
        const int row = wr + m * 16 + fr;
        const int c16 = (kk * 2 + (fg >> 1)) ^ ((row >> 1) & 3);
        af[m][kk] = *(const long long*)&Ab[row * 64 + c16 * 16 + (fg & 1) * 8];
      }
#pragma unroll
    for (int n = 0; n < 4; ++n)
#pragma unroll
      for (int kk = 0; kk < 2; ++kk) {
        const int col = wc + n * 16 + fr;
        const int c16 = (kk * 2 + (fg >> 1)) ^ ((col >> 1) & 3);
        bfr[n][kk] = *(const long long*)&Bb[col * 64 + c16 * 16 + (fg & 1) * 8];
      }
#pragma unroll
    for (int kk = 0; kk < 2; ++kk)
#pragma unroll
      for (int m = 0; m < 4; ++m)
#pragma unroll
        for (int n = 0; n < 4; ++n)
          acc[m][n] = MFMA8(af[m][kk], bfr[n][kk], acc[m][n]);
  }

  float bv[4];
#pragma unroll
  for (int n = 0; n < 4; ++n) bv[n] = bias[tn * 128 + wc + n * 16 + fr];
#pragma unroll
  for (int m = 0; m < 4; ++m)
#pragma unroll
    for (int n = 0; n < 4; ++n) {
      const long col = brow0 + wc + n * 16 + fr;
#pragma unroll
      for (int r = 0; r < 4; ++r) {
        const long row = arow0 + wr + m * 16 + fg * 4 + r;
        float v = acc[m][n][r] + bv[n];
        if (ACT == 1) v = fmaxf(v, 0.f);
        C[row * (long)N + col] = f2fp8(v);
      }
    }
}

// ============ K2 (64 rows/block): branch * trunk -> 13-dim out. 4 barriers total. ============
// A panels staged once in LDS; B operands (w3f/w4T, L2-resident) read direct to registers.
__global__ __launch_bounds__(512, 4)
void k2(const unsigned char* __restrict__ h2, const float* __restrict__ state,
        const float* __restrict__ tw1, const float* __restrict__ tb1,
        const unsigned char* __restrict__ w3f, const float* __restrict__ bb3,
        const short* __restrict__ w4T, const float* __restrict__ tb2,
        const short* __restrict__ pwT, const float* __restrict__ qw1,
        const short* __restrict__ qw2T, const float* __restrict__ qb1,
        const float* __restrict__ pb, const float* __restrict__ qb2,
        const float* __restrict__ rwp, float* __restrict__ out) {
  __shared__ __align__(16) char lds[77824];
  char*  h2S = lds;                    // [64][512] fp8 (16B-granule XOR swz): 32768
  short* tS  = (short*)(lds + 32768);  // [64][256] bf16 swz8: 32768; later inter
  short* pwS = (short*)(lds + 65536);  // [16][256] swz8: 8192
  short* q2S = (short*)(lds + 73728);  // [16][128] swz8: 4096
  short* hqS = (short*)lds;            // [64][128] swz8 (16384) — overlays h2S after branch
  float* prS = (float*)(lds + 16384);  // [64][16]
  float* pr2S= (float*)(lds + 20480);  // [64][16]

  const int tid = threadIdx.x, wave = tid >> 6, lane = tid & 63;
  const int fr = lane & 15, fg = lane >> 4;
  const long rb = (long)blockIdx.x * 64;

  // ---- stage h2 panel (pre-swizzled source), pwT, qw2T; then t-build overlaps latency ----
#pragma unroll
  for (int it = 0; it < 4; ++it) {
    int ch = it * 512 + tid;
    int row = ch >> 5, c = ch & 31;
    gl_lds16(h2 + (rb + row) * 512 + ((c ^ (row & 7)) << 4), h2S + ch * 16);
  }
  { int row = tid >> 5, c = tid & 31;
    gl_lds16(pwT + (long)row * 256 + swz8(c, row) * 8, (char*)pwS + tid * 16); }
  if (tid < 256) { int row = tid >> 4, c = tid & 15;
    gl_lds16(qw2T + (long)row * 128 + swz8(c, row) * 8, (char*)q2S + tid * 16); }

  for (int i = tid; i < 64 * 32; i += 512) {   // t = ftanh(pos @ tw1 + tb1) -> tS
    int r = i >> 5, c8 = i & 31;
    float p0 = state[(rb + r) * 13 + 0], p1 = state[(rb + r) * 13 + 1], p2 = state[(rb + r) * 13 + 2];
    short8 v;
#pragma unroll
    for (int j = 0; j < 8; ++j) {
      int jj = c8 * 8 + j;
      v[j] = f2bf(ftanh(p0 * tw1[jj] + p1 * tw1[256 + jj] + p2 * tw1[512 + jj] + tb1[jj]));
    }
    *(short8*)&tS[(r * 32 + swz8(c8, r)) * 8] = v;
  }
  __syncthreads();   // barrier 1: h2S/pwS/q2S staged (vmcnt drained), tS built

  const int col0 = wave * 32 + fr, col1 = col0 + 16;

  // ---- branch gemm: fp8, K=512, no barriers. A=h2S(LDS), B=w3f(global L2) ----
  f32x4 acc3[4][2] = {};
#pragma unroll
  for (int ks = 0; ks < 16; ++ks) {
    long long b0 = *(const long long*)&w3f[(long)col0 * 512 + ks * 32 + fg * 8];
    long long b1 = *(const long long*)&w3f[(long)col1 * 512 + ks * 32 + fg * 8];
    long long a[4];
#pragma unroll
    for (int mf = 0; mf < 4; ++mf) {
      int row = mf * 16 + fr;
      int c16 = (ks * 2 + (fg >> 1)) ^ (row & 7);
      a[mf] = *(const long long*)&h2S[row * 512 + c16 * 16 + ((fg & 1) << 3)];
    }
#pragma unroll
    for (int mf = 0; mf < 4; ++mf) {
      acc3[mf][0] = MFMA8(a[mf], b0, acc3[mf][0]);
      acc3[mf][1] = MFMA8(a[mf], b1, acc3[mf][1]);
    }
  }

  // ---- trunk gemm: bf16, K=256, no barriers. A=tS(LDS), B=w4T(global L2) ----
  f32x4 accT[4][2] = {};
#pragma unroll
  for (int ks = 0; ks < 8; ++ks) {
    short8 b0 = *(const short8*)&w4T[(long)col0 * 256 + ks * 32 + fg * 8];
    short8 b1 = *(const short8*)&w4T[(long)col1 * 256 + ks * 32 + fg * 8];
#pragma unroll
    for (int mf = 0; mf < 4; ++mf) {
      int row = mf * 16 + fr;
      short8 aF = *(const short8*)&tS[row * 256 + swz8(ks * 4 + fg, row) * 8];
      accT[mf][0] = MFMA(aF, b0, accT[mf][0]);
      accT[mf][1] = MFMA(aF, b1, accT[mf][1]);
    }
  }
  __syncthreads();   // barrier 2: all h2S/tS reads done -> regions reusable

  // ---- interaction -> tS (reuse); bias-net hq via VALU -> hqS (overlays h2S) ----
#pragma unroll
  for (int nf = 0; nf < 2; ++nf) {
    int col = wave * 32 + nf * 16 + fr;
    float b3 = bb3[col], t2 = tb2[col];
#pragma unroll
    for (int mf = 0; mf < 4; ++mf)
#pragma unroll
      for (int i = 0; i < 4; ++i) {
        int row = mf * 16 + fg * 4 + i;
        float br = acc3[mf][nf][i] + b3;
        float tr = ftanh(accT[mf][nf][i] + t2);
        tS[row * 256 + swz8(col >> 3, row) * 8 + (col & 7)] = f2bf(br * tr);
      }
  }
  {
    int r = tid >> 3, j0 = (tid & 7) * 16;
    float p0 = state[(rb + r) * 13 + 0], p1 = state[(rb + r) * 13 + 1], p2 = state[(rb + r) * 13 + 2];
#pragma unroll
    for (int cc = 0; cc < 2; ++cc) {
      short8 v;
#pragma unroll
      for (int j = 0; j < 8; ++j) {
        int jj = j0 + cc * 8 + j;
        float hv = fmaxf(p0 * qw1[jj] + p1 * qw1[128 + jj] + p2 * qw1[256 + jj] + qb1[jj], 0.f);
        v[j] = f2bf(hv);
      }
      *(short8*)&hqS[(r * 16 + swz8(j0 / 8 + cc, r)) * 8] = v;
    }
  }
  __syncthreads();   // barrier 3: inter + hq visible

  // ---- proj: waves 0-3: inter @ pwT (K=256); waves 4-7: hq @ qw2T (K=128) ----
  if (wave < 4) {
    int row = wave * 16 + fr;
    f32x4 accP = {0.f, 0.f, 0.f, 0.f};
#pragma unroll
    for (int ks = 0; ks < 8; ++ks) {
      short8 a = *(const short8*)&tS[row * 256 + swz8(ks * 4 + fg, row) * 8];
      short8 b = *(const short8*)&pwS[fr * 256 + swz8(ks * 4 + fg, fr) * 8];
      accP = MFMA(a, b, accP);
    }
#pragma unroll
    for (int i = 0; i < 4; ++i)
      prS[(wave * 16 + fg * 4 + i) * 16 + fr] = accP[i];
  } else {
    int row = (wave - 4) * 16 + fr;
    f32x4 accQ = {0.f, 0.f, 0.f, 0.f};
#pragma unroll
    for (int ks = 0; ks < 4; ++ks) {
      short8 a = *(const short8*)&hqS[row * 128 + swz8(ks * 4 + fg, row) * 8];
      short8 b = *(const short8*)&q2S[fr * 128 + swz8(ks * 4 + fg, fr) * 8];
      accQ = MFMA(a, b, accQ);
    }
#pragma unroll
    for (int i = 0; i < 4; ++i)
      pr2S[((wave - 4) * 16 + fg * 4 + i) * 16 + fr] = accQ[i];
  }
  __syncthreads();   // barrier 4

  // ---- epilogue: residual + quat normalize ----
  if (tid < 64) {
    int r = tid;
    float rw = rwp[0];
    float ns[13];
#pragma unroll
    for (int c = 0; c < 13; ++c)
      ns[c] = state[(rb + r) * 13 + c] + rw * (prS[r * 16 + c] + pr2S[r * 16 + c] + pb[c] + qb2[c]);
    float qn = sqrtf(ns[3] * ns[3] + ns[4] * ns[4] + ns[5] * ns[5] + ns[6] * ns[6]) + 1e-8f;
#pragma unroll
    for (int c = 3; c < 7; ++c) ns[c] /= qn;
#pragma unroll
    for (int c = 0; c < 13; ++c) out[(rb + r) * 13 + c] = ns[c];
  }
}

extern "C" void kernel_launch(void* const* d_in, const int* in_sizes, int n_in,
                              void* d_out, int out_size, void* d_ws, size_t ws_size,
                              hipStream_t stream) {
  const float* state  = (const float*)d_in[0];
  const float* action = (const float*)d_in[1];
  const float* sensors= (const float*)d_in[2];
  const float* bw1 = (const float*)d_in[3];
  const float* bb1 = (const float*)d_in[4];
  const float* bw2 = (const float*)d_in[5];
  const float* bb2 = (const float*)d_in[6];
  const float* bw3 = (const float*)d_in[7];
  const float* bb3 = (const float*)d_in[8];
  const float* tw1 = (const float*)d_in[9];
  const float* tb1 = (const float*)d_in[10];
  const float* tw2 = (const float*)d_in[11];
  const float* tb2 = (const float*)d_in[12];
  const float* qw1 = (const float*)d_in[13];
  const float* qb1 = (const float*)d_in[14];
  const float* qw2 = (const float*)d_in[15];
  const float* qb2 = (const float*)d_in[16];
  const float* pw  = (const float*)d_in[17];
  const float* pb  = (const float*)d_in[18];
  const float* rw  = (const float*)d_in[19];
  float* out = (float*)d_out;

  char* p = (char*)d_ws;
  unsigned char* w1f = (unsigned char*)p; p += (size_t)1024 * 576;
  unsigned char* w2f = (unsigned char*)p; p += (size_t)512 * 1024;
  unsigned char* w3f = (unsigned char*)p; p += (size_t)256 * 512;
  short* w4T = (short*)p;          p += (size_t)256 * 256 * 2;
  short* pwT = (short*)p;          p += (size_t)16 * 256 * 2;
  short* qw2T= (short*)p;          p += (size_t)16 * 128 * 2;
  const size_t fixed = (size_t)(p - (char*)d_ws);
  const size_t avail = (ws_size > fixed) ? ws_size - fixed : 0;
  // per-row: enc 576B fp8 (h2 fp8 512B overlays after gemm1) + h1f 1024B fp8
  long Mc = (long)(avail / 1600) & ~1023L;   // mult of 1024 (XCD remap: Mtiles%8==0)
  if (Mc > B_TOTAL) Mc = B_TOTAL;
  if (Mc < 1024) return;
  unsigned char* encb = (unsigned char*)p;               // Mc*576; h2 overlays
  unsigned char* h2b  = (unsigned char*)p;
  unsigned char* h1f  = (unsigned char*)(p + (size_t)Mc * 576);  // Mc*1024

  prep<<<dim3(1281), dim3(256), 0, stream>>>(bw1, bw2, bw3, tw2, pw, qw2,
                                             w1f, w2f, w3f, w4T, pwT, qw2T);

  for (long r0 = 0; r0 < B_TOTAL; r0 += Mc) {
    long Mr = B_TOTAL - r0; if (Mr > Mc) Mr = Mc;
    enc_k<<<dim3(Mr / 64), dim3(256), 0, stream>>>(state + r0 * 13, action + r0 * 4,
                                                   sensors, encb);
    gemm_f8<1024, 576, 1><<<dim3((Mr / 128) * 8), dim3(256), 0, stream>>>(
        encb, w1f, bb1, h1f);
    gemm_f8<512, 1024, 1><<<dim3((Mr / 128) * 4), dim3(256), 0, stream>>>(
        h1f, w2f, bb2, h2b);
    k2<<<dim3(Mr / 64), dim3(512), 0, stream>>>(h2b, state + r0 * 13, tw1, tb1,
                                                w3f, bb3, w4T, tb2, pwT, qw1, qw2T,
                                                qb1, pb, qb2, rw, out + r0 * 13);
  }
}

// Round 8
// 376.060 us; speedup vs baseline: 1.9678x; 1.0182x over previous
//
#include <hip/hip_runtime.h>
#include <hip/hip_bf16.h>
#include <hip/hip_fp8.h>

#define B_TOTAL 131072

typedef __attribute__((ext_vector_type(8))) short short8;   // 8 bf16 MFMA A/B frag
typedef __attribute__((ext_vector_type(4))) float f32x4;    // MFMA C/D frag
typedef __attribute__((ext_vector_type(16))) unsigned char uchar16;
typedef unsigned int uint;

#define MFMA(a,b,c) __builtin_amdgcn_mfma_f32_16x16x32_bf16(a,b,c,0,0,0)
#define MFMA8(a,b,c) __builtin_amdgcn_mfma_f32_16x16x32_fp8_fp8(a,b,c,0,0,0)

__device__ __forceinline__ short f2bf(float f) {
  union { float f; uint u; } x; x.f = f;
  uint r = x.u + 0x7fffu + ((x.u >> 16) & 1u);  // RTNE
  return (short)(r >> 16);
}
__device__ __forceinline__ unsigned char f2fp8(float v) {
  union { __hip_fp8_e4m3 q; unsigned char b; } u;
  u.q = __hip_fp8_e4m3(v);
  return u.b;
}
// fast tanh: 1 - 2/(exp(2x)+1) via v_exp_f32 + v_rcp_f32
__device__ __forceinline__ float ftanh(float x) {
  float e = __builtin_amdgcn_exp2f(x * 2.8853900817779268f);   // exp(2x)
  return 1.f - 2.f * __builtin_amdgcn_rcpf(e + 1.f);
}

__device__ __forceinline__ void gl_lds16(const void* g, void* l) {
  __builtin_amdgcn_global_load_lds((const __attribute__((address_space(1))) uint*)g,
                                   (__attribute__((address_space(3))) uint*)l, 16, 0, 0);
}
__device__ __forceinline__ int swz8(int c, int r) { return (c & ~7) | ((c ^ r) & 7); }

// ============ merged weight prep ============
// w1f[1024][576] fp8 lin | w2f[512][1024] fp8 lin | w3r frag-ordered fp8 (128KB) |
// w4r frag-ordered bf16 (128KB) | pwT/qw2T.
// Frag order: record (ks, wblk, half) of 512B(fp8)/1KB(bf16); lane l=(fg*16+fr) fragment
// at record*512 + l*8 (bytes / shorts) so k2's B loads are single coalesced transactions.
__global__ __launch_bounds__(256)
void prep(const float* __restrict__ bw1, const float* __restrict__ bw2,
          const float* __restrict__ bw3, const float* __restrict__ tw2,
          const float* __restrict__ pw, const float* __restrict__ qw2,
          unsigned char* __restrict__ w1f, unsigned char* __restrict__ w2f,
          unsigned char* __restrict__ w3r, short* __restrict__ w4r,
          short* __restrict__ pwT, short* __restrict__ qw2T) {
  __shared__ float tile[32][33];
  int b = blockIdx.x;
  if (b == 1280) {  // small weights, scattered (tiny)
    for (int t = threadIdx.x; t < 6144; t += 256) {
      if (t < 4096) { int c = t >> 8, k = t & 255;
        pwT[t] = (c < 13) ? f2bf(pw[k * 13 + c]) : (short)0; }
      else { int i = t - 4096; int c = i >> 7, j = i & 127;
        qw2T[i] = (c < 13) ? f2bf(qw2[j * 13 + c]) : (short)0; }
    }
    return;
  }
  const float* src; int K, N, mat;
  if (b < 576)       { src = bw1; K = 544;  N = 1024; mat = 0; }
  else if (b < 1088) { b -= 576;  src = bw2; K = 1024; N = 512;  mat = 1; }
  else if (b < 1216) { b -= 1088; src = bw3; K = 512;  N = 256;  mat = 2; }
  else               { b -= 1216; src = tw2; K = 256;  N = 256;  mat = 3; }
  const int ntk = (mat == 0) ? 18 : (mat == 1) ? 32 : (mat == 2) ? 16 : 8;
  const int tn = b / ntk, tk = b % ntk;
  const int k0 = tk * 32, n0 = tn * 32;
  const int tx = threadIdx.x & 31, ty = threadIdx.x >> 5;
#pragma unroll
  for (int rr = 0; rr < 32; rr += 8) {
    int k = k0 + ty + rr;
    tile[ty + rr][tx] = (k < K) ? src[(long)k * N + n0 + tx] : 0.f;
  }
  __syncthreads();
#pragma unroll
  for (int rr = 0; rr < 32; rr += 8) {
    int nl = ty + rr;
    int n = n0 + nl, k = k0 + tx;
    float v = tile[tx][nl];
    if (mat == 0) w1f[(long)n * 576 + k] = f2fp8(v);
    else if (mat == 1) w2f[(long)n * 1024 + k] = f2fp8(v);
    else {
      int ks = k >> 5, fq = (k >> 3) & 3, j = k & 7;
      int wb = n >> 5, hf = (n >> 4) & 1, fr = n & 15;
      long idx = (long)(((ks * 8 + wb) * 2 + hf) * 4 + fq) * 128 + fr * 8 + j;
      if (mat == 2) w3r[idx] = f2fp8(v);
      else          w4r[idx] = f2bf(v);
    }
  }
}

// ---- enc kernel: builds enc[M][576] fp8 (zero-padded cols 544..575) ----
__global__ __launch_bounds__(256)
void enc_k(const float* __restrict__ state, const float* __restrict__ action,
           const float* __restrict__ sensors, unsigned char* __restrict__ enc) {
  __shared__ float sval[64][17];
  __shared__ float wexp[64][32];
  __shared__ float sens[96];
  const int tid = threadIdx.x;
  const int rb = blockIdx.x * 64;
  if (tid < 96) sens[tid] = sensors[tid];
  for (int i = tid; i < 64 * 17; i += 256) {
    const int r = i / 17, c = i % 17;
    const long grow = rb + r;
    sval[r][c] = (c < 13) ? state[grow * 13 + c] : action[grow * 4 + (c - 13)];
  }
  __syncthreads();
  for (int i = tid; i < 64 * 32; i += 256) {
    const int r = i >> 5, s = i & 31;
    const float dx = sens[s*3+0] - sval[r][0];
    const float dy = sens[s*3+1] - sval[r][1];
    const float dz = sens[s*3+2] - sval[r][2];
    wexp[r][s] = __expf(-2.0f * sqrtf(dx*dx + dy*dy + dz*dz));
  }
  __syncthreads();
  for (int i = tid; i < 64 * 36; i += 256) {
    const int r = i / 36, c16 = i % 36;
    uchar16 v;
#pragma unroll
    for (int j = 0; j < 16; ++j) {
      const int k = c16 * 16 + j;
      unsigned char o = 0;
      if (k < 544) { const int s = k / 17, c = k % 17; o = f2fp8(sval[r][c] * wexp[r][s]); }
      v[j] = o;
    }
    *(uchar16*)&enc[((long)(rb + r)) * 576 + c16 * 16] = v;
  }
}

// ---- GEMM fp8 x fp8 -> fp8 (relu): 128x128 tile, BK=64, (row>>1)&3 swizzle ----
template<int N, int K, int ACT>
__global__ __launch_bounds__(256, 4)
void gemm_f8(const unsigned char* __restrict__ A, const unsigned char* __restrict__ Bt,
             const float* __restrict__ bias, unsigned char* __restrict__ C) {
  constexpr int NT = K / 64;
  constexpr int NTN = N / 128;
  __shared__ __align__(16) unsigned char As[2][128 * 64];
  __shared__ __align__(16) unsigned char Bs[2][128 * 64];
  const int tid = threadIdx.x;
  const int wave = tid >> 6;
  const int lane = tid & 63;
  const int Mtiles = gridDim.x / NTN;
  const int bid = blockIdx.x;
  const int xcd = bid & 7, seq = bid >> 3;
  const int tm = xcd * (Mtiles >> 3) + seq / NTN;
  const int tn = seq % NTN;
  const long arow0 = (long)tm * 128;
  const long brow0 = (long)tn * 128;

  auto stage = [&](int b, int kt) {
    const int k0 = kt * 64;
#pragma unroll
    for (int it = 0; it < 2; ++it) {
      const int ch = it * 256 + tid;       // 16B chunk 0..511
      const int row = ch >> 2;
      const int cs = (ch & 3) ^ ((row >> 1) & 3);
      gl_lds16(A + (arow0 + row) * (long)K + k0 + cs * 16, &As[b][ch * 16]);
      gl_lds16(Bt + (brow0 + row) * (long)K + k0 + cs * 16, &Bs[b][ch * 16]);
    }
  };

  const int wr = (wave >> 1) * 64;
  const int wc = (wave & 1) * 64;
  const int fr = lane & 15;
  const int fg = lane >> 4;

  f32x4 acc[4][4] = {};

  stage(0, 0);
  for (int kt = 0; kt < NT; ++kt) {
    const int cur = kt & 1;
    __syncthreads();
    if (kt + 1 < NT) stage(cur ^ 1, kt + 1);
    const unsigned char* Ab = As[cur];
    const unsigned char* Bb = Bs[cur];
    long long af[4][2], bfr[4][2];
#pragma unroll
    for (int m = 0; m < 4; ++m)
#pragma unroll
      for (int kk = 0; kk < 2; ++kk) {
        const int row = wr + m * 16 + fr;
        const int c16 = (kk * 2 + (fg >> 1)) ^ ((row >> 1) & 3);
        af[m][kk] = *(const long long*)&Ab[row * 64 + c16 * 16 + (fg & 1) * 8];
      }
#pragma unroll
    for (int n = 0; n < 4; ++n)
#pragma unroll
      for (int kk = 0; kk < 2; ++kk) {
        const int col = wc + n * 16 + fr;
        const int c16 = (kk * 2 + (fg >> 1)) ^ ((col >> 1) & 3);
        bfr[n][kk] = *(const long long*)&Bb[col * 64 + c16 * 16 + (fg & 1) * 8];
      }
#pragma unroll
    for (int kk = 0; kk < 2; ++kk)
#pragma unroll
      for (int m = 0; m < 4; ++m)
#pragma unroll
        for (int n = 0; n < 4; ++n)
          acc[m][n] = MFMA8(af[m][kk], bfr[n][kk], acc[m][n]);
  }

  float bv[4];
#pragma unroll
  for (int n = 0; n < 4; ++n) bv[n] = bias[tn * 128 + wc + n * 16 + fr];
#pragma unroll
  for (int m = 0; m < 4; ++m)
#pragma unroll
    for (int n = 0; n < 4; ++n) {
      const long col = brow0 + wc + n * 16 + fr;
#pragma unroll
      for (int r = 0; r < 4; ++r) {
        const long row = arow0 + wr + m * 16 + fg * 4 + r;
        float v = acc[m][n][r] + bv[n];
        if (ACT == 1) v = fmaxf(v, 0.f);
        C[row * (long)N + col] = f2fp8(v);
      }
    }
}

// ============ K2 (64 rows/block): branch * trunk -> 13-dim out ============
// B operands fully prefetched into registers from frag-ordered w3r/w4r (coalesced,
// issued at kernel top so HBM/L2 latency hides under staging + t-build).
__global__ __launch_bounds__(512)
void k2(const unsigned char* __restrict__ h2, const float* __restrict__ state,
        const float* __restrict__ tw1, const float* __restrict__ tb1,
        const unsigned char* __restrict__ w3r, const float* __restrict__ bb3,
        const short* __restrict__ w4r, const float* __restrict__ tb2,
        const short* __restrict__ pwT, const float* __restrict__ qw1,
        const short* __restrict__ qw2T, const float* __restrict__ qb1,
        const float* __restrict__ pb, const float* __restrict__ qb2,
        const float* __restrict__ rwp, float* __restrict__ out) {
  __shared__ __align__(16) char lds[77824];
  char*  h2S = lds;                    // [64][512] fp8 (16B-granule XOR swz): 32768
  short* tS  = (short*)(lds + 32768);  // [64][256] bf16 swz8: 32768; later inter
  short* pwS = (short*)(lds + 65536);  // [16][256] swz8: 8192
  short* q2S = (short*)(lds + 73728);  // [16][128] swz8: 4096
  short* hqS = (short*)lds;            // [64][128] swz8 — overlays h2S after branch
  float* prS = (float*)(lds + 16384);  // [64][16]
  float* pr2S= (float*)(lds + 20480);  // [64][16]

  const int tid = threadIdx.x, wave = tid >> 6, lane = tid & 63;
  const int fr = lane & 15, fg = lane >> 4;
  const long rb = (long)blockIdx.x * 64;

  // ---- prefetch ALL branch-B frags (each load = one coalesced 512B wave transaction) ----
  long long b3r[16][2];
#pragma unroll
  for (int ks = 0; ks < 16; ++ks) {
    b3r[ks][0] = *(const long long*)&w3r[(long)((ks * 8 + wave) * 2 + 0) * 512 + lane * 8];
    b3r[ks][1] = *(const long long*)&w3r[(long)((ks * 8 + wave) * 2 + 1) * 512 + lane * 8];
  }
  // ---- stage h2 panel (pre-swizzled source), pwT, qw2T ----
#pragma unroll
  for (int it = 0; it < 4; ++it) {
    int ch = it * 512 + tid;
    int row = ch >> 5, c = ch & 31;
    gl_lds16(h2 + (rb + row) * 512 + ((c ^ (row & 7)) << 4), h2S + ch * 16);
  }
  { int row = tid >> 5, c = tid & 31;
    gl_lds16(pwT + (long)row * 256 + swz8(c, row) * 8, (char*)pwS + tid * 16); }
  if (tid < 256) { int row = tid >> 4, c = tid & 15;
    gl_lds16(qw2T + (long)row * 128 + swz8(c, row) * 8, (char*)q2S + tid * 16); }
  // ---- prefetch trunk-B frags (1KB coalesced each) ----
  short8 b4r[8][2];
#pragma unroll
  for (int ks = 0; ks < 8; ++ks) {
    b4r[ks][0] = *(const short8*)&w4r[(long)((ks * 8 + wave) * 2 + 0) * 512 + lane * 8];
    b4r[ks][1] = *(const short8*)&w4r[(long)((ks * 8 + wave) * 2 + 1) * 512 + lane * 8];
  }

  for (int i = tid; i < 64 * 32; i += 512) {   // t = ftanh(pos @ tw1 + tb1) -> tS
    int r = i >> 5, c8 = i & 31;
    float p0 = state[(rb + r) * 13 + 0], p1 = state[(rb + r) * 13 + 1], p2 = state[(rb + r) * 13 + 2];
    short8 v;
#pragma unroll
    for (int j = 0; j < 8; ++j) {
      int jj = c8 * 8 + j;
      v[j] = f2bf(ftanh(p0 * tw1[jj] + p1 * tw1[256 + jj] + p2 * tw1[512 + jj] + tb1[jj]));
    }
    *(short8*)&tS[(r * 32 + swz8(c8, r)) * 8] = v;
  }
  __syncthreads();   // barrier 1: staging + all prefetches landed, tS built

  // ---- branch gemm: fp8, K=512 — pure LDS + MFMA ----
  f32x4 acc3[4][2] = {};
#pragma unroll
  for (int ks = 0; ks < 16; ++ks) {
    long long a[4];
#pragma unroll
    for (int mf = 0; mf < 4; ++mf) {
      int row = mf * 16 + fr;
      int c16 = (ks * 2 + (fg >> 1)) ^ (row & 7);
      a[mf] = *(const long long*)&h2S[row * 512 + c16 * 16 + ((fg & 1) << 3)];
    }
#pragma unroll
    for (int mf = 0; mf < 4; ++mf) {
      acc3[mf][0] = MFMA8(a[mf], b3r[ks][0], acc3[mf][0]);
      acc3[mf][1] = MFMA8(a[mf], b3r[ks][1], acc3[mf][1]);
    }
  }

  // ---- trunk gemm: bf16, K=256 — pure LDS + MFMA ----
  f32x4 accT[4][2] = {};
#pragma unroll
  for (int ks = 0; ks < 8; ++ks) {
#pragma unroll
    for (int mf = 0; mf < 4; ++mf) {
      int row = mf * 16 + fr;
      short8 aF = *(const short8*)&tS[row * 256 + swz8(ks * 4 + fg, row) * 8];
      accT[mf][0] = MFMA(aF, b4r[ks][0], accT[mf][0]);
      accT[mf][1] = MFMA(aF, b4r[ks][1], accT[mf][1]);
    }
  }
  __syncthreads();   // barrier 2: all h2S/tS reads done -> regions reusable

  // ---- interaction -> tS (reuse); bias-net hq via VALU -> hqS (overlays h2S) ----
#pragma unroll
  for (int nf = 0; nf < 2; ++nf) {
    int col = wave * 32 + nf * 16 + fr;
    float b3 = bb3[col], t2 = tb2[col];
#pragma unroll
    for (int mf = 0; mf < 4; ++mf)
#pragma unroll
      for (int i = 0; i < 4; ++i) {
        int row = mf * 16 + fg * 4 + i;
        float br = acc3[mf][nf][i] + b3;
        float tr = ftanh(accT[mf][nf][i] + t2);
        tS[row * 256 + swz8(col >> 3, row) * 8 + (col & 7)] = f2bf(br * tr);
      }
  }
  {
    int r = tid >> 3, j0 = (tid & 7) * 16;
    float p0 = state[(rb + r) * 13 + 0], p1 = state[(rb + r) * 13 + 1], p2 = state[(rb + r) * 13 + 2];
#pragma unroll
    for (int cc = 0; cc < 2; ++cc) {
      short8 v;
#pragma unroll
      for (int j = 0; j < 8; ++j) {
        int jj = j0 + cc * 8 + j;
        float hv = fmaxf(p0 * qw1[jj] + p1 * qw1[128 + jj] + p2 * qw1[256 + jj] + qb1[jj], 0.f);
        v[j] = f2bf(hv);
      }
      *(short8*)&hqS[(r * 16 + swz8(j0 / 8 + cc, r)) * 8] = v;
    }
  }
  __syncthreads();   // barrier 3: inter + hq visible

  // ---- proj: waves 0-3: inter @ pwT (K=256); waves 4-7: hq @ qw2T (K=128) ----
  if (wave < 4) {
    int row = wave * 16 + fr;
    f32x4 accP = {0.f, 0.f, 0.f, 0.f};
#pragma unroll
    for (int ks = 0; ks < 8; ++ks) {
      short8 a = *(const short8*)&tS[row * 256 + swz8(ks * 4 + fg, row) * 8];
      short8 b = *(const short8*)&pwS[fr * 256 + swz8(ks * 4 + fg, fr) * 8];
      accP = MFMA(a, b, accP);
    }
#pragma unroll
    for (int i = 0; i < 4; ++i)
      prS[(wave * 16 + fg * 4 + i) * 16 + fr] = accP[i];
  } else {
    int row = (wave - 4) * 16 + fr;
    f32x4 accQ = {0.f, 0.f, 0.f, 0.f};
#pragma unroll
    for (int ks = 0; ks < 4; ++ks) {
      short8 a = *(const short8*)&hqS[row * 128 + swz8(ks * 4 + fg, row) * 8];
      short8 b = *(const short8*)&q2S[fr * 128 + swz8(ks * 4 + fg, fr) * 8];
      accQ = MFMA(a, b, accQ);
    }
#pragma unroll
    for (int i = 0; i < 4; ++i)
      pr2S[((wave - 4) * 16 + fg * 4 + i) * 16 + fr] = accQ[i];
  }
  __syncthreads();   // barrier 4

  // ---- epilogue: residual + quat normalize ----
  if (tid < 64) {
    int r = tid;
    float rw = rwp[0];
    float ns[13];
#pragma unroll
    for (int c = 0; c < 13; ++c)
      ns[c] = state[(rb + r) * 13 + c] + rw * (prS[r * 16 + c] + pr2S[r * 16 + c] + pb[c] + qb2[c]);
    float qn = sqrtf(ns[3] * ns[3] + ns[4] * ns[4] + ns[5] * ns[5] + ns[6] * ns[6]) + 1e-8f;
#pragma unroll
    for (int c = 3; c < 7; ++c) ns[c] /= qn;
#pragma unroll
    for (int c = 0; c < 13; ++c) out[(rb + r) * 13 + c] = ns[c];
  }
}

extern "C" void kernel_launch(void* const* d_in, const int* in_sizes, int n_in,
                              void* d_out, int out_size, void* d_ws, size_t ws_size,
                              hipStream_t stream) {
  const float* state  = (const float*)d_in[0];
  const float* action = (const float*)d_in[1];
  const float* sensors= (const float*)d_in[2];
  const float* bw1 = (const float*)d_in[3];
  const float* bb1 = (const float*)d_in[4];
  const float* bw2 = (const float*)d_in[5];
  const float* bb2 = (const float*)d_in[6];
  const float* bw3 = (const float*)d_in[7];
  const float* bb3 = (const float*)d_in[8];
  const float* tw1 = (const float*)d_in[9];
  const float* tb1 = (const float*)d_in[10];
  const float* tw2 = (const float*)d_in[11];
  const float* tb2 = (const float*)d_in[12];
  const float* qw1 = (const float*)d_in[13];
  const float* qb1 = (const float*)d_in[14];
  const float* qw2 = (const float*)d_in[15];
  const float* qb2 = (const float*)d_in[16];
  const float* pw  = (const float*)d_in[17];
  const float* pb  = (const float*)d_in[18];
  const float* rw  = (const float*)d_in[19];
  float* out = (float*)d_out;

  char* p = (char*)d_ws;
  unsigned char* w1f = (unsigned char*)p; p += (size_t)1024 * 576;
  unsigned char* w2f = (unsigned char*)p; p += (size_t)512 * 1024;
  unsigned char* w3r = (unsigned char*)p; p += (size_t)256 * 512;
  short* w4r = (short*)p;          p += (size_t)256 * 256 * 2;
  short* pwT = (short*)p;          p += (size_t)16 * 256 * 2;
  short* qw2T= (short*)p;          p += (size_t)16 * 128 * 2;
  const size_t fixed = (size_t)(p - (char*)d_ws);
  const size_t avail = (ws_size > fixed) ? ws_size - fixed : 0;
  // per-row: enc 576B fp8 (h2 512B overlays after gemm1) + h1f 1024B fp8
  long Mc = (long)(avail / 1600) & ~1023L;   // mult of 1024 (XCD remap: Mtiles%8==0)
  if (Mc > B_TOTAL) Mc = B_TOTAL;
  if (Mc < 1024) return;
  unsigned char* encb = (unsigned char*)p;               // Mc*576; h2 overlays
  unsigned char* h2b  = (unsigned char*)p;
  unsigned char* h1f  = (unsigned char*)(p + (size_t)Mc * 576);  // Mc*1024

  prep<<<dim3(1281), dim3(256), 0, stream>>>(bw1, bw2, bw3, tw2, pw, qw2,
                                             w1f, w2f, w3r, w4r, pwT, qw2T);

  for (long r0 = 0; r0 < B_TOTAL; r0 += Mc) {
    long Mr = B_TOTAL - r0; if (Mr > Mc) Mr = Mc;
    enc_k<<<dim3(Mr / 64), dim3(256), 0, stream>>>(state + r0 * 13, action + r0 * 4,
                                                   sensors, encb);
    gemm_f8<1024, 576, 1><<<dim3((Mr / 128) * 8), dim3(256), 0, stream>>>(
        encb, w1f, bb1, h1f);
    gemm_f8<512, 1024, 1><<<dim3((Mr / 128) * 4), dim3(256), 0, stream>>>(
        h1f, w2f, bb2, h2b);
    k2<<<dim3(Mr / 64), dim3(512), 0, stream>>>(h2b, state + r0 * 13, tw1, tb1,
                                                w3r, bb3, w4r, tb2, pwT, qw1, qw2T,
                                                qb1, pb, qb2, rw, out + r0 * 13);
  }
}